// Round 1
// baseline (3907.682 us; speedup 1.0000x reference)
//
#include <hip/hip_runtime.h>
#include <math.h>

#define B_   64
#define L_   196
#define C_   768
#define K_   8192
#define R_   8
#define HW_  14
#define M_   (B_*L_)     // 12544
#define NH_  8
#define DH_  96
#define BP_  16
#define NT_  32          // cur_f * R tokens per attention sequence
#define VQ_SPLITS 8

// ---------------- utilities ----------------
__device__ inline float wave_reduce_sum(float v) {
    #pragma unroll
    for (int o = 32; o >= 1; o >>= 1) v += __shfl_xor(v, o, 64);
    return v;
}
__device__ inline float wave_reduce_max(float v) {
    #pragma unroll
    for (int o = 32; o >= 1; o >>= 1) v = fmaxf(v, __shfl_xor(v, o, 64));
    return v;
}

// ---------------- codebook norms ----------------
__global__ __launch_bounds__(64) void cnorm_kernel(const float* __restrict__ cb,
                                                   float* __restrict__ cn) {
    int k = blockIdx.x;
    const float* row = cb + (size_t)k * C_;
    float s = 0.f;
    for (int c = threadIdx.x; c < C_; c += 64) { float v = row[c]; s += v * v; }
    s = wave_reduce_sum(s);
    if (threadIdx.x == 0) cn[k] = s;
}

// ---------------- conv weight transposes (for coalesced channel reads) -------
__global__ __launch_bounds__(256) void transpose_w_kernel(const float* __restrict__ att_w,
                                                          const float* __restrict__ ex_w,
                                                          float* __restrict__ wT,
                                                          float* __restrict__ exT) {
    int gid = blockIdx.x * 256 + threadIdx.x;
    if (gid < R_ * C_ * 9) {
        int r = gid / (C_ * 9);
        int rem = gid - r * (C_ * 9);
        int c = rem / 9, tap = rem - c * 9;
        wT[((size_t)tap * R_ + r) * C_ + c] = att_w[gid];
    }
    if (gid < C_ * 9) {
        int c = gid / 9, tap = gid - c * 9;
        exT[(size_t)tap * C_ + c] = ex_w[gid];
    }
}

// ---------------- VQ argmin: fp32 tiled GEMM + running min ----------------
// grid (196, 8): 64 rows per block, 1024 codes per split. 256 threads, 4x4 micro.
__global__ __launch_bounds__(256) void vq_argmin_kernel(const float* __restrict__ X,
                                                        const float* __restrict__ CB,
                                                        const float* __restrict__ cn,
                                                        float* __restrict__ pVal,
                                                        int* __restrict__ pIdx) {
    __shared__ __align__(16) float As[64][36];
    __shared__ __align__(16) float Bs[64][36];
    const int tid = threadIdx.x;
    const int tx = tid & 15, ty = tid >> 4;
    const int row0 = blockIdx.x * 64;
    const int code0 = blockIdx.y * 1024;
    const int rl = tid >> 3, ql = (tid & 7) * 4;   // staging coords

    float minv[4];
    int   mini[4];
    #pragma unroll
    for (int i = 0; i < 4; ++i) { minv[i] = INFINITY; mini[i] = 0; }

    for (int bn = 0; bn < 1024; bn += 64) {
        const int cbase = code0 + bn;
        float acc[4][4] = {{0.f}};
        #pragma unroll 1
        for (int k0 = 0; k0 < C_; k0 += 32) {
            __syncthreads();
            *(float4*)&As[rl][ql]      = *(const float4*)&X[(size_t)(row0 + rl) * C_ + k0 + ql];
            *(float4*)&As[rl + 32][ql] = *(const float4*)&X[(size_t)(row0 + rl + 32) * C_ + k0 + ql];
            *(float4*)&Bs[rl][ql]      = *(const float4*)&CB[(size_t)(cbase + rl) * C_ + k0 + ql];
            *(float4*)&Bs[rl + 32][ql] = *(const float4*)&CB[(size_t)(cbase + rl + 32) * C_ + k0 + ql];
            __syncthreads();
            #pragma unroll
            for (int kk = 0; kk < 32; kk += 4) {
                float4 a[4], bv[4];
                #pragma unroll
                for (int i = 0; i < 4; ++i) a[i]  = *(const float4*)&As[ty + 16 * i][kk];
                #pragma unroll
                for (int j = 0; j < 4; ++j) bv[j] = *(const float4*)&Bs[tx + 16 * j][kk];
                #pragma unroll
                for (int i = 0; i < 4; ++i)
                    #pragma unroll
                    for (int j = 0; j < 4; ++j)
                        acc[i][j] += a[i].x * bv[j].x + a[i].y * bv[j].y +
                                     a[i].z * bv[j].z + a[i].w * bv[j].w;
            }
        }
        #pragma unroll
        for (int j = 0; j < 4; ++j) {
            int code = cbase + tx + 16 * j;
            float cnj = cn[code];
            #pragma unroll
            for (int i = 0; i < 4; ++i) {
                float d = cnj - 2.f * acc[i][j];          // ||x||^2 constant per row: dropped
                if (d < minv[i]) { minv[i] = d; mini[i] = code; }
            }
        }
    }
    // reduce (val,idx) across the 16 tx lanes (same ty => same rows)
    #pragma unroll
    for (int off = 8; off >= 1; off >>= 1) {
        #pragma unroll
        for (int i = 0; i < 4; ++i) {
            float ov = __shfl_xor(minv[i], off, 64);
            int   oi = __shfl_xor(mini[i], off, 64);
            if (ov < minv[i] || (ov == minv[i] && oi < mini[i])) { minv[i] = ov; mini[i] = oi; }
        }
    }
    if (tx == 0) {
        #pragma unroll
        for (int i = 0; i < 4; ++i) {
            int row = row0 + ty + 16 * i;
            pVal[(size_t)blockIdx.y * M_ + row] = minv[i];
            pIdx[(size_t)blockIdx.y * M_ + row] = mini[i];
        }
    }
}

__global__ __launch_bounds__(256) void vq_reduce_kernel(const float* __restrict__ pVal,
                                                        const int* __restrict__ pIdx,
                                                        int* __restrict__ idx,
                                                        float* __restrict__ encOut) {
    int r = blockIdx.x * 256 + threadIdx.x;
    if (r >= M_) return;
    float bv = INFINITY; int bi = 0;
    #pragma unroll
    for (int s = 0; s < VQ_SPLITS; ++s) {
        float v = pVal[(size_t)s * M_ + r];
        int i2  = pIdx[(size_t)s * M_ + r];
        if (v < bv || (v == bv && i2 < bi)) { bv = v; bi = i2; }
    }
    idx[r] = bi;
    encOut[r] = (float)bi;   // enc is stored as float in the flat f32 output buffer
}

// ---------------- motion excitation conv (C->1, 3x3 SAME on frame diff) ------
__global__ __launch_bounds__(256) void mm_conv_kernel(const float* __restrict__ X,
                                                      const float* __restrict__ exT,
                                                      const float* __restrict__ ex_b,
                                                      float* __restrict__ mm) {
    int p = blockIdx.x, b = blockIdx.y;
    if ((b & 3) == 0) {                      // first frame: diff == 0 -> bias only
        if (threadIdx.x == 0) mm[b * L_ + p] = ex_b[0];
        return;
    }
    int y = p / HW_, x = p - y * HW_;
    const float* cur = X + (size_t)b * L_ * C_;
    const float* prv = cur - (size_t)L_ * C_;
    float acc = 0.f;
    for (int c = threadIdx.x; c < C_; c += 256) {
        #pragma unroll
        for (int dy = 0; dy < 3; ++dy) {
            int yy = y + dy - 1; if (yy < 0 || yy >= HW_) continue;
            #pragma unroll
            for (int dx = 0; dx < 3; ++dx) {
                int xx = x + dx - 1; if (xx < 0 || xx >= HW_) continue;
                int pn = yy * HW_ + xx;
                float dv = cur[(size_t)pn * C_ + c] - prv[(size_t)pn * C_ + c];
                acc += dv * exT[(size_t)(dy * 3 + dx) * C_ + c];
            }
        }
    }
    acc = wave_reduce_sum(acc);
    __shared__ float red[4];
    if ((threadIdx.x & 63) == 0) red[threadIdx.x >> 6] = acc;
    __syncthreads();
    if (threadIdx.x == 0) mm[b * L_ + p] = red[0] + red[1] + red[2] + red[3] + ex_b[0];
}

__global__ __launch_bounds__(256) void softmax_kernel(const float* __restrict__ mm,
                                                      float* __restrict__ sm) {
    int b = blockIdx.x, t = threadIdx.x;
    __shared__ float red[4];
    float v = (t < L_) ? mm[b * L_ + t] : -INFINITY;
    float mw = wave_reduce_max(v);
    if ((t & 63) == 0) red[t >> 6] = mw;
    __syncthreads();
    float mx = fmaxf(fmaxf(red[0], red[1]), fmaxf(red[2], red[3]));
    float e = (t < L_) ? expf(v - mx) : 0.f;
    __syncthreads();
    float sw = wave_reduce_sum(e);
    if ((t & 63) == 0) red[t >> 6] = sw;
    __syncthreads();
    float s = red[0] + red[1] + red[2] + red[3];
    if (t < L_) sm[b * L_ + t] = e / s;
}

// ---------------- vq_final = codebook[idx] + in_feas * sm ----------------
__global__ __launch_bounds__(192) void vqf_kernel(const float* __restrict__ X,
                                                  const float* __restrict__ CB,
                                                  const int* __restrict__ idx,
                                                  const float* __restrict__ sm,
                                                  float* __restrict__ vqf) {
    int row = blockIdx.x;
    int t = threadIdx.x;                      // 192 threads * float4 = 768
    int k = idx[row];
    float s = sm[row];
    float4 xv = *(const float4*)&X[(size_t)row * C_ + t * 4];
    float4 cv = *(const float4*)&CB[(size_t)k * C_ + t * 4];
    float4 o;
    o.x = cv.x + xv.x * s; o.y = cv.y + xv.y * s;
    o.z = cv.z + xv.z * s; o.w = cv.w + xv.w * s;
    *(float4*)&vqf[(size_t)row * C_ + t * 4] = o;
}

// ---------------- region attention conv (C->8, 3x3 SAME) ----------------
__global__ __launch_bounds__(256) void rm_conv_kernel(const float* __restrict__ vqf,
                                                      const float* __restrict__ wT,
                                                      const float* __restrict__ att_b,
                                                      float* __restrict__ rmOut) {
    int p = blockIdx.x, b = blockIdx.y;
    int y = p / HW_, x = p - y * HW_;
    float acc[R_] = {};
    for (int c = threadIdx.x; c < C_; c += 256) {
        #pragma unroll
        for (int dy = 0; dy < 3; ++dy) {
            int yy = y + dy - 1; if (yy < 0 || yy >= HW_) continue;
            #pragma unroll
            for (int dx = 0; dx < 3; ++dx) {
                int xx = x + dx - 1; if (xx < 0 || xx >= HW_) continue;
                int pn = yy * HW_ + xx;
                float xv = vqf[((size_t)b * L_ + pn) * C_ + c];
                const float* wrow = wT + ((size_t)(dy * 3 + dx) * R_) * C_ + c;
                #pragma unroll
                for (int r = 0; r < R_; ++r) acc[r] += xv * wrow[(size_t)r * C_];
            }
        }
    }
    #pragma unroll
    for (int r = 0; r < R_; ++r) acc[r] = wave_reduce_sum(acc[r]);
    __shared__ float red[4][R_];
    if ((threadIdx.x & 63) == 0) {
        #pragma unroll
        for (int r = 0; r < R_; ++r) red[threadIdx.x >> 6][r] = acc[r];
    }
    __syncthreads();
    if (threadIdx.x < R_) {
        int r = threadIdx.x;
        rmOut[((size_t)b * R_ + r) * L_ + p] =
            red[0][r] + red[1][r] + red[2][r] + red[3][r] + att_b[r];
    }
}

// ---------------- regions einsum: seq[b*8+r][c] = sum_p vq*rm / 196 ----------
__global__ __launch_bounds__(256) void regions_kernel(const float* __restrict__ vqf,
                                                      const float* __restrict__ rm,
                                                      float* __restrict__ seq) {
    int b = blockIdx.x;
    __shared__ float rms[R_ * L_];
    for (int t = threadIdx.x; t < R_ * L_; t += 256) rms[t] = rm[(size_t)b * R_ * L_ + t];
    __syncthreads();
    const float inv = 1.f / 196.f;
    for (int c = threadIdx.x; c < C_; c += 256) {
        float acc[R_] = {};
        for (int p = 0; p < L_; ++p) {
            float xv = vqf[((size_t)b * L_ + p) * C_ + c];
            #pragma unroll
            for (int r = 0; r < R_; ++r) acc[r] += xv * rms[r * L_ + p];
        }
        #pragma unroll
        for (int r = 0; r < R_; ++r) seq[((size_t)b * R_ + r) * C_ + c] = acc[r] * inv;
    }
}

// ---------------- generic GEMM: out = A @ W^T + bias ----------------
__global__ __launch_bounds__(256) void gemm_bias_kernel(const float* __restrict__ A,
                                                        const float* __restrict__ Wt,
                                                        const float* __restrict__ bias,
                                                        float* __restrict__ out,
                                                        int M, int N, int K) {
    __shared__ __align__(16) float As[64][36];
    __shared__ __align__(16) float Bs[64][36];
    const int tid = threadIdx.x;
    const int tx = tid & 15, ty = tid >> 4;
    const int m0 = blockIdx.x * 64, n0 = blockIdx.y * 64;
    const int rl = tid >> 3, ql = (tid & 7) * 4;
    float acc[4][4] = {{0.f}};
    #pragma unroll 1
    for (int k0 = 0; k0 < K; k0 += 32) {
        __syncthreads();
        *(float4*)&As[rl][ql]      = *(const float4*)&A[(size_t)(m0 + rl) * K + k0 + ql];
        *(float4*)&As[rl + 32][ql] = *(const float4*)&A[(size_t)(m0 + rl + 32) * K + k0 + ql];
        *(float4*)&Bs[rl][ql]      = *(const float4*)&Wt[(size_t)(n0 + rl) * K + k0 + ql];
        *(float4*)&Bs[rl + 32][ql] = *(const float4*)&Wt[(size_t)(n0 + rl + 32) * K + k0 + ql];
        __syncthreads();
        #pragma unroll
        for (int kk = 0; kk < 32; kk += 4) {
            float4 a[4], bv[4];
            #pragma unroll
            for (int i = 0; i < 4; ++i) a[i]  = *(const float4*)&As[ty + 16 * i][kk];
            #pragma unroll
            for (int j = 0; j < 4; ++j) bv[j] = *(const float4*)&Bs[tx + 16 * j][kk];
            #pragma unroll
            for (int i = 0; i < 4; ++i)
                #pragma unroll
                for (int j = 0; j < 4; ++j)
                    acc[i][j] += a[i].x * bv[j].x + a[i].y * bv[j].y +
                                 a[i].z * bv[j].z + a[i].w * bv[j].w;
        }
    }
    #pragma unroll
    for (int i = 0; i < 4; ++i) {
        int row = m0 + ty + 16 * i;
        #pragma unroll
        for (int j = 0; j < 4; ++j) {
            int col = n0 + tx + 16 * j;
            out[(size_t)row * N + col] = acc[i][j] + bias[col];
        }
    }
}

// ---------------- per-(batch,head) attention over 32 tokens ----------------
__global__ __launch_bounds__(256) void attn_kernel(const float* __restrict__ qkv,
                                                   float* __restrict__ outb) {
    int bp = blockIdx.x, h = blockIdx.y;
    __shared__ float qs[NT_][DH_], ks[NT_][DH_], vs[NT_][DH_];
    __shared__ float sc[NT_][NT_ + 1];
    int tid = threadIdx.x;
    for (int e = tid; e < NT_ * DH_; e += 256) {
        int n = e / DH_, d = e - n * DH_;
        size_t base = ((size_t)(bp * NT_ + n)) * 2304 + h * DH_ + d;
        qs[n][d] = qkv[base];
        ks[n][d] = qkv[base + 768];
        vs[n][d] = qkv[base + 1536];
    }
    __syncthreads();
    const float scale = 1.0f / sqrtf((float)DH_);
    for (int e = tid; e < NT_ * NT_; e += 256) {
        int n = e >> 5, m = e & 31;
        float s = 0.f;
        #pragma unroll 8
        for (int d = 0; d < DH_; ++d) s += qs[n][d] * ks[m][d];
        sc[n][m] = s * scale;
    }
    __syncthreads();
    if (tid < NT_) {
        float mx = -INFINITY;
        #pragma unroll
        for (int m = 0; m < NT_; ++m) mx = fmaxf(mx, sc[tid][m]);
        float sum = 0.f;
        #pragma unroll
        for (int m = 0; m < NT_; ++m) { float e2 = expf(sc[tid][m] - mx); sc[tid][m] = e2; sum += e2; }
        float inv = 1.f / sum;
        #pragma unroll
        for (int m = 0; m < NT_; ++m) sc[tid][m] *= inv;
    }
    __syncthreads();
    for (int e = tid; e < NT_ * DH_; e += 256) {
        int n = e / DH_, d = e - n * DH_;
        float o = 0.f;
        #pragma unroll
        for (int m = 0; m < NT_; ++m) o += sc[n][m] * vs[m][d];
        outb[((size_t)(bp * NT_ + n)) * C_ + h * DH_ + d] = o;
    }
}

// ---------------- launch ----------------
extern "C" void kernel_launch(void* const* d_in, const int* in_sizes, int n_in,
                              void* d_out, int out_size, void* d_ws, size_t ws_size,
                              hipStream_t stream) {
    const float* in_feas  = (const float*)d_in[0];
    // d_in[1] = cur_f = 4 (shapes fixed; hardcoded)
    const float* codebook = (const float*)d_in[2];
    const float* att_w    = (const float*)d_in[3];
    const float* att_b    = (const float*)d_in[4];
    const float* ex_w     = (const float*)d_in[5];
    const float* ex_b     = (const float*)d_in[6];
    const float* qkv_w    = (const float*)d_in[7];
    const float* qkv_b    = (const float*)d_in[8];
    const float* proj_w   = (const float*)d_in[9];
    const float* proj_b   = (const float*)d_in[10];

    float* out    = (float*)d_out;
    float* outVd  = out;                         // [64,8,768]  = 393216
    float* outEnc = out + 393216;                // [64,14,14]  = 12544 (as float)
    float* outRm  = out + 393216 + 12544;        // [64,8,14,14]= 100352

    float* ws = (float*)d_ws;
    size_t off = 0;
    float* cn    = ws + off; off += K_;                 // 8192
    float* pVal  = ws + off; off += (size_t)VQ_SPLITS * M_;
    int*   pIdx  = (int*)(ws + off); off += (size_t)VQ_SPLITS * M_;
    int*   idx   = (int*)(ws + off); off += M_;
    float* mm    = ws + off; off += M_;
    float* sm    = ws + off; off += M_;
    float* wT    = ws + off; off += (size_t)R_ * C_ * 9;
    float* exT   = ws + off; off += (size_t)C_ * 9;
    float* vqf   = ws + off; off += (size_t)M_ * C_;    // 9.63M floats
    float* seq   = ws + off; off += (size_t)512 * C_;
    float* qkvb  = ws + off; off += (size_t)512 * 2304;
    float* attnb = ws + off; off += (size_t)512 * C_;

    hipLaunchKernelGGL(cnorm_kernel, dim3(K_), dim3(64), 0, stream, codebook, cn);
    hipLaunchKernelGGL(transpose_w_kernel, dim3(216), dim3(256), 0, stream, att_w, ex_w, wT, exT);
    hipLaunchKernelGGL(vq_argmin_kernel, dim3(M_ / 64, VQ_SPLITS), dim3(256), 0, stream,
                       in_feas, codebook, cn, pVal, pIdx);
    hipLaunchKernelGGL(vq_reduce_kernel, dim3(M_ / 256, 1), dim3(256), 0, stream,
                       pVal, pIdx, idx, outEnc);
    hipLaunchKernelGGL(mm_conv_kernel, dim3(L_, B_), dim3(256), 0, stream, in_feas, exT, ex_b, mm);
    hipLaunchKernelGGL(softmax_kernel, dim3(B_), dim3(256), 0, stream, mm, sm);
    hipLaunchKernelGGL(vqf_kernel, dim3(M_), dim3(192), 0, stream, in_feas, codebook, idx, sm, vqf);
    hipLaunchKernelGGL(rm_conv_kernel, dim3(L_, B_), dim3(256), 0, stream, vqf, wT, att_b, outRm);
    hipLaunchKernelGGL(regions_kernel, dim3(B_), dim3(256), 0, stream, vqf, outRm, seq);
    hipLaunchKernelGGL(gemm_bias_kernel, dim3(8, 36), dim3(256), 0, stream,
                       seq, qkv_w, qkv_b, qkvb, 512, 2304, 768);
    hipLaunchKernelGGL(attn_kernel, dim3(BP_, NH_), dim3(256), 0, stream, qkvb, attnb);
    hipLaunchKernelGGL(gemm_bias_kernel, dim3(8, 12), dim3(256), 0, stream,
                       attnb, proj_w, proj_b, outVd, 512, 768, 768);
}

// Round 2
// 1136.682 us; speedup vs baseline: 3.4378x; 3.4378x over previous
//
#include <hip/hip_runtime.h>
#include <math.h>

#define B_   64
#define L_   196
#define C_   768
#define K_   8192
#define R_   8
#define HW_  14
#define M_   (B_*L_)     // 12544
#define NH_  8
#define DH_  96
#define BP_  16
#define NT_  32

typedef unsigned short ushort_t;
typedef __attribute__((ext_vector_type(8))) short short8v;   // 8 bf16 (4 VGPR)
typedef __attribute__((ext_vector_type(4))) float f32x4;     // MFMA 16x16 acc

// ---------------- utilities ----------------
__device__ inline float wave_reduce_sum(float v) {
    #pragma unroll
    for (int o = 32; o >= 1; o >>= 1) v += __shfl_xor(v, o, 64);
    return v;
}
__device__ inline float wave_reduce_max(float v) {
    #pragma unroll
    for (int o = 32; o >= 1; o >>= 1) v = fmaxf(v, __shfl_xor(v, o, 64));
    return v;
}

__device__ inline ushort_t f2bf_rne(float f) {
    unsigned u = __float_as_uint(f);
    unsigned r = u + 0x7fffu + ((u >> 16) & 1u);
    return (ushort_t)(r >> 16);
}
__device__ inline float bf2f(ushort_t h) { return __uint_as_float(((unsigned)h) << 16); }

__device__ inline void gload_lds16(const void* gsrc, void* ldst) {
    __builtin_amdgcn_global_load_lds(
        (const __attribute__((address_space(1))) unsigned int*)gsrc,
        (__attribute__((address_space(3))) unsigned int*)ldst, 16, 0, 0);
}

// top-2 merge with lowest-index tie-break
__device__ inline void top2_merge(float& v1, int& i1, float& v2, int& i2,
                                  float w1, int j1, float w2, int j2) {
    bool fw = (v1 < w1) || (v1 == w1 && i1 <= j1);
    float a1 = fw ? v1 : w1;  int ai1 = fw ? i1 : j1;
    float lb = fw ? w1 : v1;  int lbi = fw ? j1 : i1;
    float wsv = fw ? v2 : w2; int wsi = fw ? i2 : j2;
    bool sb = (lb < wsv) || (lb == wsv && lbi < wsi);
    v1 = a1; i1 = ai1;
    v2 = sb ? lb : wsv; i2 = sb ? lbi : wsi;
}

// ---------------- codebook norms ----------------
__global__ __launch_bounds__(64) void cnorm_kernel(const float* __restrict__ cb,
                                                   float* __restrict__ cn) {
    int k = blockIdx.x;
    const float* row = cb + (size_t)k * C_;
    float s = 0.f;
    for (int c = threadIdx.x; c < C_; c += 64) { float v = row[c]; s += v * v; }
    s = wave_reduce_sum(s);
    if (threadIdx.x == 0) cn[k] = s;
}

// ---------------- codebook split to fragment-linear bf16 hi/lo ----------------
// layout: [cb_g(512)][kb_g(24)][lane(64)][e(8)]; code = cb_g*16+(l&15), k = kb_g*32+(l>>4)*8+e
__global__ __launch_bounds__(256) void cb_split_kernel(const float* __restrict__ CB,
                                                       ushort_t* __restrict__ CBhi,
                                                       ushort_t* __restrict__ CBlo) {
    int s = blockIdx.x * 256 + threadIdx.x;      // 786432 slots
    int cb_g = s / 1536;
    int rem = s - cb_g * 1536;
    int kb_g = rem >> 6, l = rem & 63;
    int code = (cb_g << 4) + (l & 15);
    int k = kb_g * 32 + (l >> 4) * 8;
    const float* gp = CB + (size_t)code * C_ + k;
    union { ushort_t u[8]; short8v v; } H, Lo;
    #pragma unroll
    for (int e = 0; e < 8; ++e) {
        float f = gp[e];
        ushort_t h = f2bf_rne(f);
        float lo = f - bf2f(h);
        H.u[e] = h; Lo.u[e] = f2bf_rne(lo);
    }
    *(short8v*)&CBhi[(size_t)s * 8] = H.v;
    *(short8v*)&CBlo[(size_t)s * 8] = Lo.v;
}

// ---------------- conv weight transposes ----------------
__global__ __launch_bounds__(256) void transpose_w_kernel(const float* __restrict__ att_w,
                                                          const float* __restrict__ ex_w,
                                                          float* __restrict__ wT,
                                                          float* __restrict__ exT) {
    int gid = blockIdx.x * 256 + threadIdx.x;
    if (gid < R_ * C_ * 9) {
        int r = gid / (C_ * 9);
        int rem = gid - r * (C_ * 9);
        int c = rem / 9, tap = rem - c * 9;
        wT[((size_t)tap * R_ + r) * C_ + c] = att_w[gid];
    }
    if (gid < C_ * 9) {
        int c = gid / 9, tap = gid - c * 9;
        exT[(size_t)tap * C_ + c] = ex_w[gid];
    }
}

// ---------------- VQ: 3-pass split-bf16 MFMA GEMM + running top-2 argmin -----
// grid (8, 98): blockIdx.x = code group (1024 codes, XCD-pinned), blockIdx.y = 128-row tile
__global__ __launch_bounds__(256, 2) void vq_mfma_kernel(const float* __restrict__ X,
                                                         const ushort_t* __restrict__ CBhi,
                                                         const ushort_t* __restrict__ CBlo,
                                                         const float* __restrict__ cn,
                                                         float4* __restrict__ cand) {
    __shared__ __align__(16) ushort_t Ahi[8 * 2 * 64 * 8];   // 16 KB each
    __shared__ __align__(16) ushort_t Alo[8 * 2 * 64 * 8];
    __shared__ __align__(16) ushort_t Bhi[8 * 2 * 64 * 8];
    __shared__ __align__(16) ushort_t Blo[8 * 2 * 64 * 8];

    const int tid = threadIdx.x;
    const int l = tid & 63, w = tid >> 6;
    const int wm = w >> 1, wn = w & 1;
    const int g = blockIdx.x;
    const int mt = blockIdx.y;
    const int row0 = mt * 128;

    float runv[4][4]; int runi[4][4];
    #pragma unroll
    for (int mf = 0; mf < 4; ++mf)
        #pragma unroll
        for (int rg = 0; rg < 4; ++rg) { runv[mf][rg] = INFINITY; runi[mf][rg] = 0x7fffffff; }

    for (int ch = 0; ch < 8; ++ch) {
        const int code0 = g * 1024 + ch * 128;
        f32x4 acc[4][4];
        #pragma unroll
        for (int mf = 0; mf < 4; ++mf)
            #pragma unroll
            for (int nf = 0; nf < 4; ++nf) acc[mf][nf] = (f32x4){0.f, 0.f, 0.f, 0.f};

        for (int st = 0; st < 12; ++st) {
            const int k0 = st * 64;
            __syncthreads();
            // ---- B staging: 16 subtiles (8 cb x 2 kb) hi+lo via global_load_lds ----
            #pragma unroll
            for (int i = 0; i < 4; ++i) {
                int s2 = w * 4 + i;
                int cb = s2 >> 1, kb = s2 & 1;
                int cb_g = (code0 >> 4) + cb;
                int kb_g = st * 2 + kb;
                size_t goff = (((size_t)cb_g * 24 + kb_g) * 64 + l) * 8;
                gload_lds16(&CBhi[goff], &Bhi[(size_t)s2 * 512]);
                gload_lds16(&CBlo[goff], &Blo[(size_t)s2 * 512]);
            }
            // ---- A staging: fp32 load -> hi/lo split -> fragment-linear ds_write ----
            #pragma unroll
            for (int s = 0; s < 4; ++s) {
                int row = s * 32 + w * 8 + (l >> 3);
                int o = l & 7;
                const float* gp = &X[(size_t)(row0 + row) * C_ + k0 + o * 8];
                union { ushort_t u[8]; short8v v; } H, Lo;
                #pragma unroll
                for (int e = 0; e < 8; ++e) {
                    float f = gp[e];
                    ushort_t h = f2bf_rne(f);
                    float lo = f - bf2f(h);
                    H.u[e] = h; Lo.u[e] = f2bf_rne(lo);
                }
                int rb = row >> 4, rr = row & 15;
                int kb = o >> 2, kg = o & 3;
                int off = (((rb * 2 + kb) * 64) + kg * 16 + rr) * 8;
                *(short8v*)&Ahi[off] = H.v;
                *(short8v*)&Alo[off] = Lo.v;
            }
            __syncthreads();
            // ---- compute: 2 k-frags x (16 ds_read_b128 + 48 MFMA) ----
            #pragma unroll
            for (int kf = 0; kf < 2; ++kf) {
                short8v ah[4], al[4], bh[4], bl[4];
                #pragma unroll
                for (int mf = 0; mf < 4; ++mf) {
                    int rb = wm * 4 + mf;
                    int off = ((rb * 2 + kf) * 64 + l) * 8;
                    ah[mf] = *(const short8v*)&Ahi[off];
                    al[mf] = *(const short8v*)&Alo[off];
                }
                #pragma unroll
                for (int nf = 0; nf < 4; ++nf) {
                    int cb = wn * 4 + nf;
                    int off = ((cb * 2 + kf) * 64 + l) * 8;
                    bh[nf] = *(const short8v*)&Bhi[off];
                    bl[nf] = *(const short8v*)&Blo[off];
                }
                #pragma unroll
                for (int mf = 0; mf < 4; ++mf)
                    #pragma unroll
                    for (int nf = 0; nf < 4; ++nf) {
                        acc[mf][nf] = __builtin_amdgcn_mfma_f32_16x16x32_bf16(ah[mf], bh[nf], acc[mf][nf], 0, 0, 0);
                        acc[mf][nf] = __builtin_amdgcn_mfma_f32_16x16x32_bf16(ah[mf], bl[nf], acc[mf][nf], 0, 0, 0);
                        acc[mf][nf] = __builtin_amdgcn_mfma_f32_16x16x32_bf16(al[mf], bh[nf], acc[mf][nf], 0, 0, 0);
                    }
            }
        }
        // ---- chunk epilogue: d = cn - 2*dot, running per-(mf,reg) min ----
        #pragma unroll
        for (int nf = 0; nf < 4; ++nf) {
            int code = code0 + wn * 64 + nf * 16 + (l & 15);
            float cnv = cn[code];
            #pragma unroll
            for (int mf = 0; mf < 4; ++mf)
                #pragma unroll
                for (int rg = 0; rg < 4; ++rg) {
                    float d = fmaf(-2.f, acc[mf][nf][rg], cnv);
                    if (d < runv[mf][rg]) { runv[mf][rg] = d; runi[mf][rg] = code; }
                }
        }
    }
    // ---- final: top-2 across the 16 col-lanes, write candidates ----
    #pragma unroll
    for (int mf = 0; mf < 4; ++mf)
        #pragma unroll
        for (int rg = 0; rg < 4; ++rg) {
            float v1 = runv[mf][rg], v2 = INFINITY;
            int i1 = runi[mf][rg], i2 = 0x7fffffff;
            #pragma unroll
            for (int off = 8; off >= 1; off >>= 1) {
                float w1 = __shfl_xor(v1, off, 64), w2 = __shfl_xor(v2, off, 64);
                int j1 = __shfl_xor(i1, off, 64), j2 = __shfl_xor(i2, off, 64);
                top2_merge(v1, i1, v2, i2, w1, j1, w2, j2);
            }
            if ((l & 15) == 0) {
                int row = row0 + wm * 64 + mf * 16 + (l >> 4) * 4 + rg;
                cand[(size_t)row * 16 + g * 2 + wn] =
                    make_float4(v1, __int_as_float(i1), v2, __int_as_float(i2));
            }
        }
}

// ---------------- exact fp64 rescore of global approx-top-2 ----------------
__global__ __launch_bounds__(256) void rescore_kernel(const float4* __restrict__ cand,
                                                      const float* __restrict__ X,
                                                      const float* __restrict__ CB,
                                                      int* __restrict__ idx,
                                                      float* __restrict__ encOut) {
    int w = threadIdx.x >> 6, l = threadIdx.x & 63;
    int r = blockIdx.x * 4 + w;
    float v1, v2; int i1, i2;
    if (l < 16) {
        float4 c = cand[(size_t)r * 16 + l];
        v1 = c.x; i1 = __float_as_int(c.y); v2 = c.z; i2 = __float_as_int(c.w);
    } else { v1 = INFINITY; v2 = INFINITY; i1 = 0x7fffffff; i2 = 0x7fffffff; }
    #pragma unroll
    for (int off = 8; off >= 1; off >>= 1) {
        float w1 = __shfl_xor(v1, off, 64), w2 = __shfl_xor(v2, off, 64);
        int j1 = __shfl_xor(i1, off, 64), j2 = __shfl_xor(i2, off, 64);
        top2_merge(v1, i1, v2, i2, w1, j1, w2, j2);
    }
    int k1 = __shfl(i1, 0, 64), k2 = __shfl(i2, 0, 64);
    double d1 = 0, d2 = 0, n1 = 0, n2 = 0;
    #pragma unroll
    for (int j = 0; j < 12; ++j) {
        int c = l * 12 + j;
        double x = (double)X[(size_t)r * C_ + c];
        double a = (double)CB[(size_t)k1 * C_ + c];
        double b = (double)CB[(size_t)k2 * C_ + c];
        d1 += x * a; d2 += x * b; n1 += a * a; n2 += b * b;
    }
    #pragma unroll
    for (int off = 32; off >= 1; off >>= 1) {
        d1 += __shfl_xor(d1, off, 64); d2 += __shfl_xor(d2, off, 64);
        n1 += __shfl_xor(n1, off, 64); n2 += __shfl_xor(n2, off, 64);
    }
    if (l == 0) {
        double dd1 = n1 - 2.0 * d1, dd2 = n2 - 2.0 * d2;
        int kw = (dd2 < dd1 || (dd2 == dd1 && k2 < k1)) ? k2 : k1;
        idx[r] = kw;
        encOut[r] = (float)kw;
    }
}

// ---------------- motion excitation conv ----------------
__global__ __launch_bounds__(256) void mm_conv_kernel(const float* __restrict__ X,
                                                      const float* __restrict__ exT,
                                                      const float* __restrict__ ex_b,
                                                      float* __restrict__ mm) {
    int p = blockIdx.x, b = blockIdx.y;
    if ((b & 3) == 0) {
        if (threadIdx.x == 0) mm[b * L_ + p] = ex_b[0];
        return;
    }
    int y = p / HW_, x = p - y * HW_;
    const float* cur = X + (size_t)b * L_ * C_;
    const float* prv = cur - (size_t)L_ * C_;
    float acc = 0.f;
    for (int c = threadIdx.x; c < C_; c += 256) {
        #pragma unroll
        for (int dy = 0; dy < 3; ++dy) {
            int yy = y + dy - 1; if (yy < 0 || yy >= HW_) continue;
            #pragma unroll
            for (int dx = 0; dx < 3; ++dx) {
                int xx = x + dx - 1; if (xx < 0 || xx >= HW_) continue;
                int pn = yy * HW_ + xx;
                float dv = cur[(size_t)pn * C_ + c] - prv[(size_t)pn * C_ + c];
                acc += dv * exT[(size_t)(dy * 3 + dx) * C_ + c];
            }
        }
    }
    acc = wave_reduce_sum(acc);
    __shared__ float red[4];
    if ((threadIdx.x & 63) == 0) red[threadIdx.x >> 6] = acc;
    __syncthreads();
    if (threadIdx.x == 0) mm[b * L_ + p] = red[0] + red[1] + red[2] + red[3] + ex_b[0];
}

__global__ __launch_bounds__(256) void softmax_kernel(const float* __restrict__ mm,
                                                      float* __restrict__ sm) {
    int b = blockIdx.x, t = threadIdx.x;
    __shared__ float red[4];
    float v = (t < L_) ? mm[b * L_ + t] : -INFINITY;
    float mw = wave_reduce_max(v);
    if ((t & 63) == 0) red[t >> 6] = mw;
    __syncthreads();
    float mx = fmaxf(fmaxf(red[0], red[1]), fmaxf(red[2], red[3]));
    float e = (t < L_) ? expf(v - mx) : 0.f;
    __syncthreads();
    float sw = wave_reduce_sum(e);
    if ((t & 63) == 0) red[t >> 6] = sw;
    __syncthreads();
    float s = red[0] + red[1] + red[2] + red[3];
    if (t < L_) sm[b * L_ + t] = e / s;
}

// ---------------- vq_final = codebook[idx] + in_feas * sm ----------------
__global__ __launch_bounds__(192) void vqf_kernel(const float* __restrict__ X,
                                                  const float* __restrict__ CB,
                                                  const int* __restrict__ idx,
                                                  const float* __restrict__ sm,
                                                  float* __restrict__ vqf) {
    int row = blockIdx.x;
    int t = threadIdx.x;
    int k = idx[row];
    float s = sm[row];
    float4 xv = *(const float4*)&X[(size_t)row * C_ + t * 4];
    float4 cv = *(const float4*)&CB[(size_t)k * C_ + t * 4];
    float4 o;
    o.x = cv.x + xv.x * s; o.y = cv.y + xv.y * s;
    o.z = cv.z + xv.z * s; o.w = cv.w + xv.w * s;
    *(float4*)&vqf[(size_t)row * C_ + t * 4] = o;
}

// ---------------- region attention conv (C->8) ----------------
__global__ __launch_bounds__(256) void rm_conv_kernel(const float* __restrict__ vqf,
                                                      const float* __restrict__ wT,
                                                      const float* __restrict__ att_b,
                                                      float* __restrict__ rmOut) {
    int p = blockIdx.x, b = blockIdx.y;
    int y = p / HW_, x = p - y * HW_;
    float acc[R_] = {};
    for (int c = threadIdx.x; c < C_; c += 256) {
        #pragma unroll
        for (int dy = 0; dy < 3; ++dy) {
            int yy = y + dy - 1; if (yy < 0 || yy >= HW_) continue;
            #pragma unroll
            for (int dx = 0; dx < 3; ++dx) {
                int xx = x + dx - 1; if (xx < 0 || xx >= HW_) continue;
                int pn = yy * HW_ + xx;
                float xv = vqf[((size_t)b * L_ + pn) * C_ + c];
                const float* wrow = wT + ((size_t)(dy * 3 + dx) * R_) * C_ + c;
                #pragma unroll
                for (int r = 0; r < R_; ++r) acc[r] += xv * wrow[(size_t)r * C_];
            }
        }
    }
    #pragma unroll
    for (int r = 0; r < R_; ++r) acc[r] = wave_reduce_sum(acc[r]);
    __shared__ float red[4][R_];
    if ((threadIdx.x & 63) == 0) {
        #pragma unroll
        for (int r = 0; r < R_; ++r) red[threadIdx.x >> 6][r] = acc[r];
    }
    __syncthreads();
    if (threadIdx.x < R_) {
        int r = threadIdx.x;
        rmOut[((size_t)b * R_ + r) * L_ + p] =
            red[0][r] + red[1][r] + red[2][r] + red[3][r] + att_b[r];
    }
}

// ---------------- regions einsum ----------------
__global__ __launch_bounds__(256) void regions_kernel(const float* __restrict__ vqf,
                                                      const float* __restrict__ rm,
                                                      float* __restrict__ seq) {
    int b = blockIdx.x;
    __shared__ float rms[R_ * L_];
    for (int t = threadIdx.x; t < R_ * L_; t += 256) rms[t] = rm[(size_t)b * R_ * L_ + t];
    __syncthreads();
    const float inv = 1.f / 196.f;
    for (int c = threadIdx.x; c < C_; c += 256) {
        float acc[R_] = {};
        for (int p = 0; p < L_; ++p) {
            float xv = vqf[((size_t)b * L_ + p) * C_ + c];
            #pragma unroll
            for (int r = 0; r < R_; ++r) acc[r] += xv * rms[r * L_ + p];
        }
        #pragma unroll
        for (int r = 0; r < R_; ++r) seq[((size_t)b * R_ + r) * C_ + c] = acc[r] * inv;
    }
}

// ---------------- generic fp32 GEMM: out = A @ W^T + bias ----------------
__global__ __launch_bounds__(256) void gemm_bias_kernel(const float* __restrict__ A,
                                                        const float* __restrict__ Wt,
                                                        const float* __restrict__ bias,
                                                        float* __restrict__ out,
                                                        int M, int N, int K) {
    __shared__ __align__(16) float As[64][36];
    __shared__ __align__(16) float Bs[64][36];
    const int tid = threadIdx.x;
    const int tx = tid & 15, ty = tid >> 4;
    const int m0 = blockIdx.x * 64, n0 = blockIdx.y * 64;
    const int rl = tid >> 3, ql = (tid & 7) * 4;
    float acc[4][4] = {{0.f}};
    #pragma unroll 1
    for (int k0 = 0; k0 < K; k0 += 32) {
        __syncthreads();
        *(float4*)&As[rl][ql]      = *(const float4*)&A[(size_t)(m0 + rl) * K + k0 + ql];
        *(float4*)&As[rl + 32][ql] = *(const float4*)&A[(size_t)(m0 + rl + 32) * K + k0 + ql];
        *(float4*)&Bs[rl][ql]      = *(const float4*)&Wt[(size_t)(n0 + rl) * K + k0 + ql];
        *(float4*)&Bs[rl + 32][ql] = *(const float4*)&Wt[(size_t)(n0 + rl + 32) * K + k0 + ql];
        __syncthreads();
        #pragma unroll
        for (int kk = 0; kk < 32; kk += 4) {
            float4 a[4], bv[4];
            #pragma unroll
            for (int i = 0; i < 4; ++i) a[i]  = *(const float4*)&As[ty + 16 * i][kk];
            #pragma unroll
            for (int j = 0; j < 4; ++j) bv[j] = *(const float4*)&Bs[tx + 16 * j][kk];
            #pragma unroll
            for (int i = 0; i < 4; ++i)
                #pragma unroll
                for (int j = 0; j < 4; ++j)
                    acc[i][j] += a[i].x * bv[j].x + a[i].y * bv[j].y +
                                 a[i].z * bv[j].z + a[i].w * bv[j].w;
        }
    }
    #pragma unroll
    for (int i = 0; i < 4; ++i) {
        int row = m0 + ty + 16 * i;
        #pragma unroll
        for (int j = 0; j < 4; ++j) {
            int col = n0 + tx + 16 * j;
            out[(size_t)row * N + col] = acc[i][j] + bias[col];
        }
    }
}

// ---------------- per-(batch,head) attention over 32 tokens ----------------
__global__ __launch_bounds__(256) void attn_kernel(const float* __restrict__ qkv,
                                                   float* __restrict__ outb) {
    int bp = blockIdx.x, h = blockIdx.y;
    __shared__ float qs[NT_][DH_], ks[NT_][DH_], vs[NT_][DH_];
    __shared__ float sc[NT_][NT_ + 1];
    int tid = threadIdx.x;
    for (int e = tid; e < NT_ * DH_; e += 256) {
        int n = e / DH_, d = e - n * DH_;
        size_t base = ((size_t)(bp * NT_ + n)) * 2304 + h * DH_ + d;
        qs[n][d] = qkv[base];
        ks[n][d] = qkv[base + 768];
        vs[n][d] = qkv[base + 1536];
    }
    __syncthreads();
    const float scale = 1.0f / sqrtf((float)DH_);
    for (int e = tid; e < NT_ * NT_; e += 256) {
        int n = e >> 5, m = e & 31;
        float s = 0.f;
        #pragma unroll 8
        for (int d = 0; d < DH_; ++d) s += qs[n][d] * ks[m][d];
        sc[n][m] = s * scale;
    }
    __syncthreads();
    if (tid < NT_) {
        float mx = -INFINITY;
        #pragma unroll
        for (int m = 0; m < NT_; ++m) mx = fmaxf(mx, sc[tid][m]);
        float sum = 0.f;
        #pragma unroll
        for (int m = 0; m < NT_; ++m) { float e2 = expf(sc[tid][m] - mx); sc[tid][m] = e2; sum += e2; }
        float inv = 1.f / sum;
        #pragma unroll
        for (int m = 0; m < NT_; ++m) sc[tid][m] *= inv;
    }
    __syncthreads();
    for (int e = tid; e < NT_ * DH_; e += 256) {
        int n = e / DH_, d = e - n * DH_;
        float o = 0.f;
        #pragma unroll
        for (int m = 0; m < NT_; ++m) o += sc[n][m] * vs[m][d];
        outb[((size_t)(bp * NT_ + n)) * C_ + h * DH_ + d] = o;
    }
}

// ---------------- launch ----------------
extern "C" void kernel_launch(void* const* d_in, const int* in_sizes, int n_in,
                              void* d_out, int out_size, void* d_ws, size_t ws_size,
                              hipStream_t stream) {
    const float* in_feas  = (const float*)d_in[0];
    const float* codebook = (const float*)d_in[2];
    const float* att_w    = (const float*)d_in[3];
    const float* att_b    = (const float*)d_in[4];
    const float* ex_w     = (const float*)d_in[5];
    const float* ex_b     = (const float*)d_in[6];
    const float* qkv_w    = (const float*)d_in[7];
    const float* qkv_b    = (const float*)d_in[8];
    const float* proj_w   = (const float*)d_in[9];
    const float* proj_b   = (const float*)d_in[10];

    float* out    = (float*)d_out;
    float* outVd  = out;
    float* outEnc = out + 393216;
    float* outRm  = out + 393216 + 12544;

    float* ws = (float*)d_ws;
    // region R1 (reused): [0 .. 9,633,792) floats
    ushort_t* CBhi = (ushort_t*)(ws + 0);              // 6,291,456 ushorts
    ushort_t* CBlo = (ushort_t*)(ws + 3145728);
    float*    cn   = ws + 6291456;                     // 8192
    float4*   cand = (float4*)(ws + 6299648);          // 12544*16 float4
    float*    vqf  = ws + 0;                           // aliases CB/cn/cand after rescore
    float*    qkvb = ws + 0;                           // aliases vqf after regions
    float*    attnb= ws + 2000000;
    // tail region (never aliased)
    int*   idx = (int*)(ws + 9633792);
    float* mm  = ws + 9646336;
    float* sm  = ws + 9658880;
    float* wT  = ws + 9671424;
    float* exT = ws + 9726720;
    float* seq = ws + 9733632;                         // ends 10,126,848 floats (40.5 MB)

    hipLaunchKernelGGL(cnorm_kernel, dim3(K_), dim3(64), 0, stream, codebook, cn);
    hipLaunchKernelGGL(cb_split_kernel, dim3(3072), dim3(256), 0, stream, codebook, CBhi, CBlo);
    hipLaunchKernelGGL(transpose_w_kernel, dim3(216), dim3(256), 0, stream, att_w, ex_w, wT, exT);
    hipLaunchKernelGGL(vq_mfma_kernel, dim3(8, 98), dim3(256), 0, stream,
                       in_feas, CBhi, CBlo, cn, cand);
    hipLaunchKernelGGL(rescore_kernel, dim3(M_ / 4), dim3(256), 0, stream,
                       cand, in_feas, codebook, idx, outEnc);
    hipLaunchKernelGGL(mm_conv_kernel, dim3(L_, B_), dim3(256), 0, stream, in_feas, exT, ex_b, mm);
    hipLaunchKernelGGL(softmax_kernel, dim3(B_), dim3(256), 0, stream, mm, sm);
    hipLaunchKernelGGL(vqf_kernel, dim3(M_), dim3(192), 0, stream, in_feas, codebook, idx, sm, vqf);
    hipLaunchKernelGGL(rm_conv_kernel, dim3(L_, B_), dim3(256), 0, stream, vqf, wT, att_b, outRm);
    hipLaunchKernelGGL(regions_kernel, dim3(B_), dim3(256), 0, stream, vqf, outRm, seq);
    hipLaunchKernelGGL(gemm_bias_kernel, dim3(8, 36), dim3(256), 0, stream,
                       seq, qkv_w, qkv_b, qkvb, 512, 2304, 768);
    hipLaunchKernelGGL(attn_kernel, dim3(BP_, NH_), dim3(256), 0, stream, qkvb, attnb);
    hipLaunchKernelGGL(gemm_bias_kernel, dim3(8, 12), dim3(256), 0, stream,
                       attnb, proj_w, proj_b, outVd, 512, 768, 768);
}

// Round 3
// 913.491 us; speedup vs baseline: 4.2777x; 1.2443x over previous
//
#include <hip/hip_runtime.h>
#include <math.h>

#define B_   64
#define L_   196
#define C_   768
#define K_   8192
#define R_   8
#define HW_  14
#define M_   (B_*L_)     // 12544
#define NH_  8
#define DH_  96
#define BP_  16
#define NT_  32

typedef unsigned short ushort_t;
typedef __attribute__((ext_vector_type(8))) short short8v;   // 8 bf16 (4 VGPR)
typedef __attribute__((ext_vector_type(4))) float f32x4;     // MFMA 16x16 acc

// ---------------- utilities ----------------
__device__ inline float wave_reduce_sum(float v) {
    #pragma unroll
    for (int o = 32; o >= 1; o >>= 1) v += __shfl_xor(v, o, 64);
    return v;
}
__device__ inline float wave_reduce_max(float v) {
    #pragma unroll
    for (int o = 32; o >= 1; o >>= 1) v = fmaxf(v, __shfl_xor(v, o, 64));
    return v;
}

__device__ inline ushort_t f2bf_rne(float f) {
    unsigned u = __float_as_uint(f);
    unsigned r = u + 0x7fffu + ((u >> 16) & 1u);
    return (ushort_t)(r >> 16);
}
__device__ inline float bf2f(ushort_t h) { return __uint_as_float(((unsigned)h) << 16); }

__device__ inline void gload_lds16(const void* gsrc, void* ldst) {
    __builtin_amdgcn_global_load_lds(
        (const __attribute__((address_space(1))) unsigned int*)gsrc,
        (__attribute__((address_space(3))) unsigned int*)ldst, 16, 0, 0);
}

// top-2 merge with lowest-index tie-break
__device__ inline void top2_merge(float& v1, int& i1, float& v2, int& i2,
                                  float w1, int j1, float w2, int j2) {
    bool fw = (v1 < w1) || (v1 == w1 && i1 <= j1);
    float a1 = fw ? v1 : w1;  int ai1 = fw ? i1 : j1;
    float lb = fw ? w1 : v1;  int lbi = fw ? j1 : i1;
    float wsv = fw ? v2 : w2; int wsi = fw ? i2 : j2;
    bool sb = (lb < wsv) || (lb == wsv && lbi < wsi);
    v1 = a1; i1 = ai1;
    v2 = sb ? lb : wsv; i2 = sb ? lbi : wsi;
}

// ---------------- codebook norms ----------------
__global__ __launch_bounds__(64) void cnorm_kernel(const float* __restrict__ cb,
                                                   float* __restrict__ cn) {
    int k = blockIdx.x;
    const float* row = cb + (size_t)k * C_;
    float s = 0.f;
    for (int c = threadIdx.x; c < C_; c += 64) { float v = row[c]; s += v * v; }
    s = wave_reduce_sum(s);
    if (threadIdx.x == 0) cn[k] = s;
}

// ---------------- codebook split to fragment-linear bf16 hi/lo ----------------
// layout: [cb_g(512)][kb_g(24)][lane(64)][e(8)]; code = cb_g*16+(l&15), k = kb_g*32+(l>>4)*8+e
__global__ __launch_bounds__(256) void cb_split_kernel(const float* __restrict__ CB,
                                                       ushort_t* __restrict__ CBhi,
                                                       ushort_t* __restrict__ CBlo) {
    int s = blockIdx.x * 256 + threadIdx.x;      // 786432 slots
    int cb_g = s / 1536;
    int rem = s - cb_g * 1536;
    int kb_g = rem >> 6, l = rem & 63;
    int code = (cb_g << 4) + (l & 15);
    int k = kb_g * 32 + (l >> 4) * 8;
    const float* gp = CB + (size_t)code * C_ + k;
    union { ushort_t u[8]; short8v v; } H, Lo;
    #pragma unroll
    for (int e = 0; e < 8; ++e) {
        float f = gp[e];
        ushort_t h = f2bf_rne(f);
        float lo = f - bf2f(h);
        H.u[e] = h; Lo.u[e] = f2bf_rne(lo);
    }
    *(short8v*)&CBhi[(size_t)s * 8] = H.v;
    *(short8v*)&CBlo[(size_t)s * 8] = Lo.v;
}

// ---------------- A split: fragment-linear bf16 hi/lo of in_feas -------------
// layout: [row_g(784)][kb(24)][lane(64)][e(8)]; row = row_g*16+(l&15), k = kb*32+(l>>4)*8+e
__global__ __launch_bounds__(256) void a_split_kernel(const float* __restrict__ X,
                                                      ushort_t* __restrict__ Ahi,
                                                      ushort_t* __restrict__ Alo) {
    __shared__ float xs[16 * 776];               // padded stride vs bank aliasing
    const int t = threadIdx.x;
    const int rg = blockIdx.x;
    const float4* src = (const float4*)(X + (size_t)rg * 16 * C_);
    #pragma unroll
    for (int i = 0; i < 12; ++i) {
        int idx4 = t + i * 256;                  // 3072 float4
        int r = idx4 / 192, c4 = idx4 - r * 192;
        ((float4*)(xs + r * 776))[c4] = src[idx4];
    }
    __syncthreads();
    #pragma unroll
    for (int i = 0; i < 6; ++i) {
        int s = t + i * 256;                     // 1536 slots
        int kb = s >> 6, l = s & 63;
        int r = l & 15;
        int k = kb * 32 + (l >> 4) * 8;
        const float* xp = &xs[r * 776 + k];
        union { ushort_t u[8]; short8v v; } H, Lo;
        #pragma unroll
        for (int e = 0; e < 8; ++e) {
            float f = xp[e];
            ushort_t h = f2bf_rne(f);
            float lo = f - bf2f(h);
            H.u[e] = h; Lo.u[e] = f2bf_rne(lo);
        }
        size_t goff = (((size_t)rg * 24 + kb) * 64 + l) * 8;
        *(short8v*)&Ahi[goff] = H.v;
        *(short8v*)&Alo[goff] = Lo.v;
    }
}

// ---------------- conv weight transposes ----------------
__global__ __launch_bounds__(256) void transpose_w_kernel(const float* __restrict__ att_w,
                                                          const float* __restrict__ ex_w,
                                                          float* __restrict__ wT,
                                                          float* __restrict__ exT) {
    int gid = blockIdx.x * 256 + threadIdx.x;
    if (gid < R_ * C_ * 9) {
        int r = gid / (C_ * 9);
        int rem = gid - r * (C_ * 9);
        int c = rem / 9, tap = rem - c * 9;
        wT[((size_t)tap * R_ + r) * C_ + c] = att_w[gid];
    }
    if (gid < C_ * 9) {
        int c = gid / 9, tap = gid - c * 9;
        exT[(size_t)tap * C_ + c] = ex_w[gid];
    }
}

// ---------------- VQ: 3-pass split-bf16 MFMA GEMM, pure global_load_lds ------
// grid (8, 98): blockIdx.x = code group (1024 codes, XCD-pinned), blockIdx.y = 128-row tile
__global__ __launch_bounds__(256, 2) void vq_mfma_kernel(const ushort_t* __restrict__ Ahi_g,
                                                         const ushort_t* __restrict__ Alo_g,
                                                         const ushort_t* __restrict__ CBhi,
                                                         const ushort_t* __restrict__ CBlo,
                                                         const float* __restrict__ cn,
                                                         float4* __restrict__ cand) {
    __shared__ __align__(16) ushort_t Ahi[16 * 512];   // 16 KB each
    __shared__ __align__(16) ushort_t Alo[16 * 512];
    __shared__ __align__(16) ushort_t Bhi[16 * 512];
    __shared__ __align__(16) ushort_t Blo[16 * 512];

    const int tid = threadIdx.x;
    const int l = tid & 63, w = tid >> 6;
    const int wm = w >> 1, wn = w & 1;
    const int g = blockIdx.x;
    const int mt = blockIdx.y;
    const int row0 = mt * 128;
    const int rg0 = mt * 8;                      // first 16-row group of this tile

    float runv[4][4]; int runi[4][4];
    #pragma unroll
    for (int mf = 0; mf < 4; ++mf)
        #pragma unroll
        for (int rg = 0; rg < 4; ++rg) { runv[mf][rg] = INFINITY; runi[mf][rg] = 0x7fffffff; }

    for (int ch = 0; ch < 8; ++ch) {
        const int code0 = g * 1024 + ch * 128;
        f32x4 acc[4][4];
        #pragma unroll
        for (int mf = 0; mf < 4; ++mf)
            #pragma unroll
            for (int nf = 0; nf < 4; ++nf) acc[mf][nf] = (f32x4){0.f, 0.f, 0.f, 0.f};

        for (int st = 0; st < 12; ++st) {
            __syncthreads();
            // ---- stage 16 subtiles each of A and B (hi+lo) via global_load_lds ----
            #pragma unroll
            for (int i = 0; i < 4; ++i) {
                int s2 = w * 4 + i;                       // 0..15: (blk>>1, kb=blk&1)
                int blk = s2 >> 1, kb = s2 & 1;
                int kbg = st * 2 + kb;
                size_t aoff = (((size_t)(rg0 + blk) * 24 + kbg) * 64 + l) * 8;
                size_t boff = (((size_t)((code0 >> 4) + blk) * 24 + kbg) * 64 + l) * 8;
                gload_lds16(&Ahi_g[aoff], &Ahi[(size_t)s2 * 512]);
                gload_lds16(&Alo_g[aoff], &Alo[(size_t)s2 * 512]);
                gload_lds16(&CBhi[boff], &Bhi[(size_t)s2 * 512]);
                gload_lds16(&CBlo[boff], &Blo[(size_t)s2 * 512]);
            }
            __syncthreads();
            // ---- compute: 2 k-frags x (16 ds_read_b128 + 48 MFMA) ----
            #pragma unroll
            for (int kf = 0; kf < 2; ++kf) {
                short8v ah[4], al[4], bh[4], bl[4];
                #pragma unroll
                for (int mf = 0; mf < 4; ++mf) {
                    int rb = wm * 4 + mf;
                    int off = ((rb * 2 + kf) * 64 + l) * 8;
                    ah[mf] = *(const short8v*)&Ahi[off];
                    al[mf] = *(const short8v*)&Alo[off];
                }
                #pragma unroll
                for (int nf = 0; nf < 4; ++nf) {
                    int cb = wn * 4 + nf;
                    int off = ((cb * 2 + kf) * 64 + l) * 8;
                    bh[nf] = *(const short8v*)&Bhi[off];
                    bl[nf] = *(const short8v*)&Blo[off];
                }
                #pragma unroll
                for (int mf = 0; mf < 4; ++mf)
                    #pragma unroll
                    for (int nf = 0; nf < 4; ++nf) {
                        acc[mf][nf] = __builtin_amdgcn_mfma_f32_16x16x32_bf16(ah[mf], bh[nf], acc[mf][nf], 0, 0, 0);
                        acc[mf][nf] = __builtin_amdgcn_mfma_f32_16x16x32_bf16(ah[mf], bl[nf], acc[mf][nf], 0, 0, 0);
                        acc[mf][nf] = __builtin_amdgcn_mfma_f32_16x16x32_bf16(al[mf], bh[nf], acc[mf][nf], 0, 0, 0);
                    }
            }
        }
        // ---- chunk epilogue: d = cn - 2*dot, running per-(mf,reg) min ----
        #pragma unroll
        for (int nf = 0; nf < 4; ++nf) {
            int code = code0 + wn * 64 + nf * 16 + (l & 15);
            float cnv = cn[code];
            #pragma unroll
            for (int mf = 0; mf < 4; ++mf)
                #pragma unroll
                for (int rg = 0; rg < 4; ++rg) {
                    float d = fmaf(-2.f, acc[mf][nf][rg], cnv);
                    if (d < runv[mf][rg]) { runv[mf][rg] = d; runi[mf][rg] = code; }
                }
        }
    }
    // ---- final: top-2 across the 16 col-lanes, write candidates ----
    #pragma unroll
    for (int mf = 0; mf < 4; ++mf)
        #pragma unroll
        for (int rg = 0; rg < 4; ++rg) {
            float v1 = runv[mf][rg], v2 = INFINITY;
            int i1 = runi[mf][rg], i2 = 0x7fffffff;
            #pragma unroll
            for (int off = 8; off >= 1; off >>= 1) {
                float w1 = __shfl_xor(v1, off, 64), w2 = __shfl_xor(v2, off, 64);
                int j1 = __shfl_xor(i1, off, 64), j2 = __shfl_xor(i2, off, 64);
                top2_merge(v1, i1, v2, i2, w1, j1, w2, j2);
            }
            if ((l & 15) == 0) {
                int row = row0 + wm * 64 + mf * 16 + (l >> 4) * 4 + rg;
                cand[(size_t)row * 16 + g * 2 + wn] =
                    make_float4(v1, __int_as_float(i1), v2, __int_as_float(i2));
            }
        }
}

// ---------------- exact fp64 rescore of global approx-top-2 ----------------
__global__ __launch_bounds__(256) void rescore_kernel(const float4* __restrict__ cand,
                                                      const float* __restrict__ X,
                                                      const float* __restrict__ CB,
                                                      int* __restrict__ idx,
                                                      float* __restrict__ encOut) {
    int w = threadIdx.x >> 6, l = threadIdx.x & 63;
    int r = blockIdx.x * 4 + w;
    float v1, v2; int i1, i2;
    if (l < 16) {
        float4 c = cand[(size_t)r * 16 + l];
        v1 = c.x; i1 = __float_as_int(c.y); v2 = c.z; i2 = __float_as_int(c.w);
    } else { v1 = INFINITY; v2 = INFINITY; i1 = 0x7fffffff; i2 = 0x7fffffff; }
    #pragma unroll
    for (int off = 8; off >= 1; off >>= 1) {
        float w1 = __shfl_xor(v1, off, 64), w2 = __shfl_xor(v2, off, 64);
        int j1 = __shfl_xor(i1, off, 64), j2 = __shfl_xor(i2, off, 64);
        top2_merge(v1, i1, v2, i2, w1, j1, w2, j2);
    }
    int k1 = __shfl(i1, 0, 64), k2 = __shfl(i2, 0, 64);
    double d1 = 0, d2 = 0, n1 = 0, n2 = 0;
    #pragma unroll
    for (int j = 0; j < 12; ++j) {
        int c = l * 12 + j;
        double x = (double)X[(size_t)r * C_ + c];
        double a = (double)CB[(size_t)k1 * C_ + c];
        double b = (double)CB[(size_t)k2 * C_ + c];
        d1 += x * a; d2 += x * b; n1 += a * a; n2 += b * b;
    }
    #pragma unroll
    for (int off = 32; off >= 1; off >>= 1) {
        d1 += __shfl_xor(d1, off, 64); d2 += __shfl_xor(d2, off, 64);
        n1 += __shfl_xor(n1, off, 64); n2 += __shfl_xor(n2, off, 64);
    }
    if (l == 0) {
        double dd1 = n1 - 2.0 * d1, dd2 = n2 - 2.0 * d2;
        int kw = (dd2 < dd1 || (dd2 == dd1 && k2 < k1)) ? k2 : k1;
        idx[r] = kw;
        encOut[r] = (float)kw;
    }
}

// ---------------- motion excitation conv ----------------
__global__ __launch_bounds__(256) void mm_conv_kernel(const float* __restrict__ X,
                                                      const float* __restrict__ exT,
                                                      const float* __restrict__ ex_b,
                                                      float* __restrict__ mm) {
    int p = blockIdx.x, b = blockIdx.y;
    if ((b & 3) == 0) {
        if (threadIdx.x == 0) mm[b * L_ + p] = ex_b[0];
        return;
    }
    int y = p / HW_, x = p - y * HW_;
    const float* cur = X + (size_t)b * L_ * C_;
    const float* prv = cur - (size_t)L_ * C_;
    float acc = 0.f;
    for (int c = threadIdx.x; c < C_; c += 256) {
        #pragma unroll
        for (int dy = 0; dy < 3; ++dy) {
            int yy = y + dy - 1; if (yy < 0 || yy >= HW_) continue;
            #pragma unroll
            for (int dx = 0; dx < 3; ++dx) {
                int xx = x + dx - 1; if (xx < 0 || xx >= HW_) continue;
                int pn = yy * HW_ + xx;
                float dv = cur[(size_t)pn * C_ + c] - prv[(size_t)pn * C_ + c];
                acc += dv * exT[(size_t)(dy * 3 + dx) * C_ + c];
            }
        }
    }
    acc = wave_reduce_sum(acc);
    __shared__ float red[4];
    if ((threadIdx.x & 63) == 0) red[threadIdx.x >> 6] = acc;
    __syncthreads();
    if (threadIdx.x == 0) mm[b * L_ + p] = red[0] + red[1] + red[2] + red[3] + ex_b[0];
}

__global__ __launch_bounds__(256) void softmax_kernel(const float* __restrict__ mm,
                                                      float* __restrict__ sm) {
    int b = blockIdx.x, t = threadIdx.x;
    __shared__ float red[4];
    float v = (t < L_) ? mm[b * L_ + t] : -INFINITY;
    float mw = wave_reduce_max(v);
    if ((t & 63) == 0) red[t >> 6] = mw;
    __syncthreads();
    float mx = fmaxf(fmaxf(red[0], red[1]), fmaxf(red[2], red[3]));
    float e = (t < L_) ? expf(v - mx) : 0.f;
    __syncthreads();
    float sw = wave_reduce_sum(e);
    if ((t & 63) == 0) red[t >> 6] = sw;
    __syncthreads();
    float s = red[0] + red[1] + red[2] + red[3];
    if (t < L_) sm[b * L_ + t] = e / s;
}

// ---------------- vq_final = codebook[idx] + in_feas * sm ----------------
__global__ __launch_bounds__(192) void vqf_kernel(const float* __restrict__ X,
                                                  const float* __restrict__ CB,
                                                  const int* __restrict__ idx,
                                                  const float* __restrict__ sm,
                                                  float* __restrict__ vqf) {
    int row = blockIdx.x;
    int t = threadIdx.x;
    int k = idx[row];
    float s = sm[row];
    float4 xv = *(const float4*)&X[(size_t)row * C_ + t * 4];
    float4 cv = *(const float4*)&CB[(size_t)k * C_ + t * 4];
    float4 o;
    o.x = cv.x + xv.x * s; o.y = cv.y + xv.y * s;
    o.z = cv.z + xv.z * s; o.w = cv.w + xv.w * s;
    *(float4*)&vqf[(size_t)row * C_ + t * 4] = o;
}

// ---------------- region attention conv (C->8) ----------------
__global__ __launch_bounds__(256) void rm_conv_kernel(const float* __restrict__ vqf,
                                                      const float* __restrict__ wT,
                                                      const float* __restrict__ att_b,
                                                      float* __restrict__ rmOut) {
    int p = blockIdx.x, b = blockIdx.y;
    int y = p / HW_, x = p - y * HW_;
    float acc[R_] = {};
    for (int c = threadIdx.x; c < C_; c += 256) {
        #pragma unroll
        for (int dy = 0; dy < 3; ++dy) {
            int yy = y + dy - 1; if (yy < 0 || yy >= HW_) continue;
            #pragma unroll
            for (int dx = 0; dx < 3; ++dx) {
                int xx = x + dx - 1; if (xx < 0 || xx >= HW_) continue;
                int pn = yy * HW_ + xx;
                float xv = vqf[((size_t)b * L_ + pn) * C_ + c];
                const float* wrow = wT + ((size_t)(dy * 3 + dx) * R_) * C_ + c;
                #pragma unroll
                for (int r = 0; r < R_; ++r) acc[r] += xv * wrow[(size_t)r * C_];
            }
        }
    }
    #pragma unroll
    for (int r = 0; r < R_; ++r) acc[r] = wave_reduce_sum(acc[r]);
    __shared__ float red[4][R_];
    if ((threadIdx.x & 63) == 0) {
        #pragma unroll
        for (int r = 0; r < R_; ++r) red[threadIdx.x >> 6][r] = acc[r];
    }
    __syncthreads();
    if (threadIdx.x < R_) {
        int r = threadIdx.x;
        rmOut[((size_t)b * R_ + r) * L_ + p] =
            red[0][r] + red[1][r] + red[2][r] + red[3][r] + att_b[r];
    }
}

// ---------------- regions einsum ----------------
__global__ __launch_bounds__(256) void regions_kernel(const float* __restrict__ vqf,
                                                      const float* __restrict__ rm,
                                                      float* __restrict__ seq) {
    int b = blockIdx.x;
    __shared__ float rms[R_ * L_];
    for (int t = threadIdx.x; t < R_ * L_; t += 256) rms[t] = rm[(size_t)b * R_ * L_ + t];
    __syncthreads();
    const float inv = 1.f / 196.f;
    for (int c = threadIdx.x; c < C_; c += 256) {
        float acc[R_] = {};
        for (int p = 0; p < L_; ++p) {
            float xv = vqf[((size_t)b * L_ + p) * C_ + c];
            #pragma unroll
            for (int r = 0; r < R_; ++r) acc[r] += xv * rms[r * L_ + p];
        }
        #pragma unroll
        for (int r = 0; r < R_; ++r) seq[((size_t)b * R_ + r) * C_ + c] = acc[r] * inv;
    }
}

// ---------------- generic fp32 GEMM: out = A @ W^T + bias ----------------
__global__ __launch_bounds__(256) void gemm_bias_kernel(const float* __restrict__ A,
                                                        const float* __restrict__ Wt,
                                                        const float* __restrict__ bias,
                                                        float* __restrict__ out,
                                                        int M, int N, int K) {
    __shared__ __align__(16) float As[64][36];
    __shared__ __align__(16) float Bs[64][36];
    const int tid = threadIdx.x;
    const int tx = tid & 15, ty = tid >> 4;
    const int m0 = blockIdx.x * 64, n0 = blockIdx.y * 64;
    const int rl = tid >> 3, ql = (tid & 7) * 4;
    float acc[4][4] = {{0.f}};
    #pragma unroll 1
    for (int k0 = 0; k0 < K; k0 += 32) {
        __syncthreads();
        *(float4*)&As[rl][ql]      = *(const float4*)&A[(size_t)(m0 + rl) * K + k0 + ql];
        *(float4*)&As[rl + 32][ql] = *(const float4*)&A[(size_t)(m0 + rl + 32) * K + k0 + ql];
        *(float4*)&Bs[rl][ql]      = *(const float4*)&Wt[(size_t)(n0 + rl) * K + k0 + ql];
        *(float4*)&Bs[rl + 32][ql] = *(const float4*)&Wt[(size_t)(n0 + rl + 32) * K + k0 + ql];
        __syncthreads();
        #pragma unroll
        for (int kk = 0; kk < 32; kk += 4) {
            float4 a[4], bv[4];
            #pragma unroll
            for (int i = 0; i < 4; ++i) a[i]  = *(const float4*)&As[ty + 16 * i][kk];
            #pragma unroll
            for (int j = 0; j < 4; ++j) bv[j] = *(const float4*)&Bs[tx + 16 * j][kk];
            #pragma unroll
            for (int i = 0; i < 4; ++i)
                #pragma unroll
                for (int j = 0; j < 4; ++j)
                    acc[i][j] += a[i].x * bv[j].x + a[i].y * bv[j].y +
                                 a[i].z * bv[j].z + a[i].w * bv[j].w;
        }
    }
    #pragma unroll
    for (int i = 0; i < 4; ++i) {
        int row = m0 + ty + 16 * i;
        #pragma unroll
        for (int j = 0; j < 4; ++j) {
            int col = n0 + tx + 16 * j;
            out[(size_t)row * N + col] = acc[i][j] + bias[col];
        }
    }
}

// ---------------- per-(batch,head) attention over 32 tokens ----------------
__global__ __launch_bounds__(256) void attn_kernel(const float* __restrict__ qkv,
                                                   float* __restrict__ outb) {
    int bp = blockIdx.x, h = blockIdx.y;
    __shared__ float qs[NT_][DH_], ks[NT_][DH_], vs[NT_][DH_];
    __shared__ float sc[NT_][NT_ + 1];
    int tid = threadIdx.x;
    for (int e = tid; e < NT_ * DH_; e += 256) {
        int n = e / DH_, d = e - n * DH_;
        size_t base = ((size_t)(bp * NT_ + n)) * 2304 + h * DH_ + d;
        qs[n][d] = qkv[base];
        ks[n][d] = qkv[base + 768];
        vs[n][d] = qkv[base + 1536];
    }
    __syncthreads();
    const float scale = 1.0f / sqrtf((float)DH_);
    for (int e = tid; e < NT_ * NT_; e += 256) {
        int n = e >> 5, m = e & 31;
        float s = 0.f;
        #pragma unroll 8
        for (int d = 0; d < DH_; ++d) s += qs[n][d] * ks[m][d];
        sc[n][m] = s * scale;
    }
    __syncthreads();
    if (tid < NT_) {
        float mx = -INFINITY;
        #pragma unroll
        for (int m = 0; m < NT_; ++m) mx = fmaxf(mx, sc[tid][m]);
        float sum = 0.f;
        #pragma unroll
        for (int m = 0; m < NT_; ++m) { float e2 = expf(sc[tid][m] - mx); sc[tid][m] = e2; sum += e2; }
        float inv = 1.f / sum;
        #pragma unroll
        for (int m = 0; m < NT_; ++m) sc[tid][m] *= inv;
    }
    __syncthreads();
    for (int e = tid; e < NT_ * DH_; e += 256) {
        int n = e / DH_, d = e - n * DH_;
        float o = 0.f;
        #pragma unroll
        for (int m = 0; m < NT_; ++m) o += sc[n][m] * vs[m][d];
        outb[((size_t)(bp * NT_ + n)) * C_ + h * DH_ + d] = o;
    }
}

// ---------------- launch ----------------
extern "C" void kernel_launch(void* const* d_in, const int* in_sizes, int n_in,
                              void* d_out, int out_size, void* d_ws, size_t ws_size,
                              hipStream_t stream) {
    const float* in_feas  = (const float*)d_in[0];
    const float* codebook = (const float*)d_in[2];
    const float* att_w    = (const float*)d_in[3];
    const float* att_b    = (const float*)d_in[4];
    const float* ex_w     = (const float*)d_in[5];
    const float* ex_b     = (const float*)d_in[6];
    const float* qkv_w    = (const float*)d_in[7];
    const float* qkv_b    = (const float*)d_in[8];
    const float* proj_w   = (const float*)d_in[9];
    const float* proj_b   = (const float*)d_in[10];

    float* out    = (float*)d_out;
    float* outVd  = out;
    float* outEnc = out + 393216;
    float* outRm  = out + 393216 + 12544;

    float* ws = (float*)d_ws;
    // live during vq: CB split (25.2MB) + cn + cand + A split (38.5MB)
    ushort_t* CBhi = (ushort_t*)(ws + 0);              // 3,145,728 floats
    ushort_t* CBlo = (ushort_t*)(ws + 3145728);
    float*    cn   = ws + 6291456;                     // 8192
    float4*   cand = (float4*)(ws + 6299648);          // 802,816 floats
    ushort_t* Ahi  = (ushort_t*)(ws + 7102464);        // 4,816,896 floats
    ushort_t* Alo  = (ushort_t*)(ws + 11919360);
    // tail (never aliased)
    int*   idx = (int*)(ws + 16736256);
    float* mm  = ws + 16748800;
    float* sm  = ws + 16761344;
    float* wT  = ws + 16773888;
    float* exT = ws + 16829184;
    float* seq = ws + 16836096;                        // ends 17,229,312 floats (68.9 MB)
    // aliases of dead split buffers:
    float* vqf   = ws + 0;                             // 9,633,792 floats (after rescore)
    float* qkvb  = ws + 0;                             // after regions (vqf dead)
    float* attnb = ws + 2000000;

    hipLaunchKernelGGL(cnorm_kernel, dim3(K_), dim3(64), 0, stream, codebook, cn);
    hipLaunchKernelGGL(cb_split_kernel, dim3(3072), dim3(256), 0, stream, codebook, CBhi, CBlo);
    hipLaunchKernelGGL(a_split_kernel, dim3(784), dim3(256), 0, stream, in_feas, Ahi, Alo);
    hipLaunchKernelGGL(transpose_w_kernel, dim3(216), dim3(256), 0, stream, att_w, ex_w, wT, exT);
    hipLaunchKernelGGL(vq_mfma_kernel, dim3(8, 98), dim3(256), 0, stream,
                       Ahi, Alo, CBhi, CBlo, cn, cand);
    hipLaunchKernelGGL(rescore_kernel, dim3(M_ / 4), dim3(256), 0, stream,
                       cand, in_feas, codebook, idx, outEnc);
    hipLaunchKernelGGL(mm_conv_kernel, dim3(L_, B_), dim3(256), 0, stream, in_feas, exT, ex_b, mm);
    hipLaunchKernelGGL(softmax_kernel, dim3(B_), dim3(256), 0, stream, mm, sm);
    hipLaunchKernelGGL(vqf_kernel, dim3(M_), dim3(192), 0, stream, in_feas, codebook, idx, sm, vqf);
    hipLaunchKernelGGL(rm_conv_kernel, dim3(L_, B_), dim3(256), 0, stream, vqf, wT, att_b, outRm);
    hipLaunchKernelGGL(regions_kernel, dim3(B_), dim3(256), 0, stream, vqf, outRm, seq);
    hipLaunchKernelGGL(gemm_bias_kernel, dim3(8, 36), dim3(256), 0, stream,
                       seq, qkv_w, qkv_b, qkvb, 512, 2304, 768);
    hipLaunchKernelGGL(attn_kernel, dim3(BP_, NH_), dim3(256), 0, stream, qkvb, attnb);
    hipLaunchKernelGGL(gemm_bias_kernel, dim3(8, 12), dim3(256), 0, stream,
                       attnb, proj_w, proj_b, outVd, 512, 768, 768);
}

// Round 4
// 806.957 us; speedup vs baseline: 4.8425x; 1.1320x over previous
//
#include <hip/hip_runtime.h>
#include <math.h>

#define B_   64
#define L_   196
#define C_   768
#define K_   8192
#define R_   8
#define HW_  14
#define M_   (B_*L_)     // 12544
#define NH_  8
#define DH_  96
#define BP_  16
#define NT_  32

typedef unsigned short ushort_t;
typedef __attribute__((ext_vector_type(8))) short short8v;   // 8 bf16 (4 VGPR)
typedef __attribute__((ext_vector_type(4))) float f32x4;     // MFMA 16x16 acc

// ---------------- utilities ----------------
__device__ inline float wave_reduce_sum(float v) {
    #pragma unroll
    for (int o = 32; o >= 1; o >>= 1) v += __shfl_xor(v, o, 64);
    return v;
}
__device__ inline float wave_reduce_max(float v) {
    #pragma unroll
    for (int o = 32; o >= 1; o >>= 1) v = fmaxf(v, __shfl_xor(v, o, 64));
    return v;
}

__device__ inline ushort_t f2bf_rne(float f) {
    unsigned u = __float_as_uint(f);
    unsigned r = u + 0x7fffu + ((u >> 16) & 1u);
    return (ushort_t)(r >> 16);
}
__device__ inline float bf2f(ushort_t h) { return __uint_as_float(((unsigned)h) << 16); }

__device__ inline void gload_lds16(const void* gsrc, void* ldst) {
    __builtin_amdgcn_global_load_lds(
        (const __attribute__((address_space(1))) unsigned int*)gsrc,
        (__attribute__((address_space(3))) unsigned int*)ldst, 16, 0, 0);
}

// top-2 merge with lowest-index tie-break
__device__ inline void top2_merge(float& v1, int& i1, float& v2, int& i2,
                                  float w1, int j1, float w2, int j2) {
    bool fw = (v1 < w1) || (v1 == w1 && i1 <= j1);
    float a1 = fw ? v1 : w1;  int ai1 = fw ? i1 : j1;
    float lb = fw ? w1 : v1;  int lbi = fw ? j1 : i1;
    float wsv = fw ? v2 : w2; int wsi = fw ? i2 : j2;
    bool sb = (lb < wsv) || (lb == wsv && lbi < wsi);
    v1 = a1; i1 = ai1;
    v2 = sb ? lb : wsv; i2 = sb ? lbi : wsi;
}

// ---------------- codebook norms ----------------
__global__ __launch_bounds__(64) void cnorm_kernel(const float* __restrict__ cb,
                                                   float* __restrict__ cn) {
    int k = blockIdx.x;
    const float* row = cb + (size_t)k * C_;
    float s = 0.f;
    for (int c = threadIdx.x; c < C_; c += 64) { float v = row[c]; s += v * v; }
    s = wave_reduce_sum(s);
    if (threadIdx.x == 0) cn[k] = s;
}

// ---------------- codebook split to fragment-linear bf16 hi/lo ----------------
// layout: [cb_g(512)][kb_g(24)][lane(64)][e(8)]; code = cb_g*16+(l&15), k = kb_g*32+(l>>4)*8+e
__global__ __launch_bounds__(256) void cb_split_kernel(const float* __restrict__ CB,
                                                       ushort_t* __restrict__ CBhi,
                                                       ushort_t* __restrict__ CBlo) {
    int s = blockIdx.x * 256 + threadIdx.x;      // 786432 slots
    int cb_g = s / 1536;
    int rem = s - cb_g * 1536;
    int kb_g = rem >> 6, l = rem & 63;
    int code = (cb_g << 4) + (l & 15);
    int k = kb_g * 32 + (l >> 4) * 8;
    const float* gp = CB + (size_t)code * C_ + k;
    union { ushort_t u[8]; short8v v; } H, Lo;
    #pragma unroll
    for (int e = 0; e < 8; ++e) {
        float f = gp[e];
        ushort_t h = f2bf_rne(f);
        float lo = f - bf2f(h);
        H.u[e] = h; Lo.u[e] = f2bf_rne(lo);
    }
    *(short8v*)&CBhi[(size_t)s * 8] = H.v;
    *(short8v*)&CBlo[(size_t)s * 8] = Lo.v;
}

// ---------------- A split: fragment-linear bf16 hi/lo of in_feas -------------
// layout: [row_g(784)][kb(24)][lane(64)][e(8)]; row = row_g*16+(l&15), k = kb*32+(l>>4)*8+e
__global__ __launch_bounds__(256) void a_split_kernel(const float* __restrict__ X,
                                                      ushort_t* __restrict__ Ahi,
                                                      ushort_t* __restrict__ Alo) {
    __shared__ float xs[16 * 776];
    const int t = threadIdx.x;
    const int rg = blockIdx.x;
    const float4* src = (const float4*)(X + (size_t)rg * 16 * C_);
    #pragma unroll
    for (int i = 0; i < 12; ++i) {
        int idx4 = t + i * 256;
        int r = idx4 / 192, c4 = idx4 - r * 192;
        ((float4*)(xs + r * 776))[c4] = src[idx4];
    }
    __syncthreads();
    #pragma unroll
    for (int i = 0; i < 6; ++i) {
        int s = t + i * 256;
        int kb = s >> 6, l = s & 63;
        int r = l & 15;
        int k = kb * 32 + (l >> 4) * 8;
        const float* xp = &xs[r * 776 + k];
        union { ushort_t u[8]; short8v v; } H, Lo;
        #pragma unroll
        for (int e = 0; e < 8; ++e) {
            float f = xp[e];
            ushort_t h = f2bf_rne(f);
            float lo = f - bf2f(h);
            H.u[e] = h; Lo.u[e] = f2bf_rne(lo);
        }
        size_t goff = (((size_t)rg * 24 + kb) * 64 + l) * 8;
        *(short8v*)&Ahi[goff] = H.v;
        *(short8v*)&Alo[goff] = Lo.v;
    }
}

// ---------------- conv weight splits (fragment-linear) ----------------
// att: [cb(5)][kb(24)][l][e]: col = cb*16+(l&15) = tap*8+r (<72), k = channel
// ex:  [cb(1)][kb(24)][l][e]: col = l&15 = tap (<9)
__global__ __launch_bounds__(256) void wsplit_kernel(const float* __restrict__ att_w,
                                                     const float* __restrict__ ex_w,
                                                     ushort_t* __restrict__ attHi,
                                                     ushort_t* __restrict__ attLo,
                                                     ushort_t* __restrict__ exHi,
                                                     ushort_t* __restrict__ exLo) {
    int gid = blockIdx.x * 256 + threadIdx.x;
    if (gid >= 9216) return;
    union { ushort_t u[8]; short8v v; } H, Lo;
    if (gid < 7680) {                                  // att: 5*24*64 slots
        int cb = gid / 1536;
        int rem = gid - cb * 1536;
        int l = rem & 63;
        int col = cb * 16 + (l & 15);
        int k = ((rem >> 6) << 5) + ((l >> 4) << 3);
        #pragma unroll
        for (int e = 0; e < 8; ++e) {
            int c = k + e;
            float f = (col < 72) ? att_w[(size_t)(col & 7) * 6912 + c * 9 + (col >> 3)] : 0.f;
            ushort_t h = f2bf_rne(f);
            H.u[e] = h; Lo.u[e] = f2bf_rne(f - bf2f(h));
        }
        *(short8v*)&attHi[(size_t)gid * 8] = H.v;
        *(short8v*)&attLo[(size_t)gid * 8] = Lo.v;
    } else {                                           // ex: 1*24*64 slots
        int g2 = gid - 7680;
        int l = g2 & 63;
        int col = l & 15;
        int k = ((g2 >> 6) << 5) + ((l >> 4) << 3);
        #pragma unroll
        for (int e = 0; e < 8; ++e) {
            int c = k + e;
            float f = (col < 9) ? ex_w[c * 9 + col] : 0.f;
            ushort_t h = f2bf_rne(f);
            H.u[e] = h; Lo.u[e] = f2bf_rne(f - bf2f(h));
        }
        *(short8v*)&exHi[(size_t)g2 * 8] = H.v;
        *(short8v*)&exLo[(size_t)g2 * 8] = Lo.v;
    }
}

// ---------------- VQ: 3-pass split-bf16 MFMA, BN=256/chunk, BK=32 ----------
// grid (8, 98): g = code split (1024 codes, XCD-pinned), mt = 128-row tile
__global__ __launch_bounds__(256, 2) void vq_mfma_kernel(const ushort_t* __restrict__ Ahi_g,
                                                         const ushort_t* __restrict__ Alo_g,
                                                         const ushort_t* __restrict__ CBhi,
                                                         const ushort_t* __restrict__ CBlo,
                                                         const float* __restrict__ cn,
                                                         float4* __restrict__ cand) {
    __shared__ __align__(16) ushort_t AhL[8 * 512];    // 8 KB
    __shared__ __align__(16) ushort_t AlL[8 * 512];
    __shared__ __align__(16) ushort_t BhL[16 * 512];   // 16 KB
    __shared__ __align__(16) ushort_t BlL[16 * 512];

    const int tid = threadIdx.x;
    const int l = tid & 63, w = tid >> 6;
    const int wm = w >> 1, wn = w & 1;
    const int g = blockIdx.x;
    const int mt = blockIdx.y;
    const int row0 = mt * 128;
    const int rg0 = mt * 8;

    float runv[4][4]; int runi[4][4];
    #pragma unroll
    for (int mf = 0; mf < 4; ++mf)
        #pragma unroll
        for (int rg = 0; rg < 4; ++rg) { runv[mf][rg] = INFINITY; runi[mf][rg] = 0x7fffffff; }

    #pragma unroll 1
    for (int ch = 0; ch < 4; ++ch) {
        const int code0 = g * 1024 + ch * 256;
        const int cbase = (code0 >> 4);                // 16 col-subtile groups
        f32x4 acc[4][8];
        #pragma unroll
        for (int mf = 0; mf < 4; ++mf)
            #pragma unroll
            for (int nf = 0; nf < 8; ++nf) acc[mf][nf] = (f32x4){0.f, 0.f, 0.f, 0.f};

        #pragma unroll 1
        for (int st = 0; st < 24; ++st) {
            __syncthreads();
            // ---- stage 48 1KB subtiles: A(8 hi + 8 lo) + B(16 hi + 16 lo) ----
            #pragma unroll
            for (int i = 0; i < 12; ++i) {
                int s = w * 12 + i;
                if (s < 8) {
                    size_t goff = (((size_t)(rg0 + s) * 24 + st) << 9) + l * 8;
                    gload_lds16(&Ahi_g[goff], &AhL[s << 9]);
                } else if (s < 16) {
                    int rb = s - 8;
                    size_t goff = (((size_t)(rg0 + rb) * 24 + st) << 9) + l * 8;
                    gload_lds16(&Alo_g[goff], &AlL[rb << 9]);
                } else if (s < 32) {
                    int cb = s - 16;
                    size_t goff = (((size_t)(cbase + cb) * 24 + st) << 9) + l * 8;
                    gload_lds16(&CBhi[goff], &BhL[cb << 9]);
                } else {
                    int cb = s - 32;
                    size_t goff = (((size_t)(cbase + cb) * 24 + st) << 9) + l * 8;
                    gload_lds16(&CBlo[goff], &BlL[cb << 9]);
                }
            }
            __syncthreads();
            // ---- compute: 8 A ds_reads + per-nf B reads, 96 MFMA/wave ----
            short8v ah[4], al[4];
            #pragma unroll
            for (int mf = 0; mf < 4; ++mf) {
                int off = ((wm * 4 + mf) << 9) + l * 8;
                ah[mf] = *(const short8v*)&AhL[off];
                al[mf] = *(const short8v*)&AlL[off];
            }
            #pragma unroll
            for (int nf = 0; nf < 8; ++nf) {
                int off = ((wn * 8 + nf) << 9) + l * 8;
                short8v bh = *(const short8v*)&BhL[off];
                short8v bl = *(const short8v*)&BlL[off];
                #pragma unroll
                for (int mf = 0; mf < 4; ++mf) {
                    acc[mf][nf] = __builtin_amdgcn_mfma_f32_16x16x32_bf16(ah[mf], bh, acc[mf][nf], 0, 0, 0);
                    acc[mf][nf] = __builtin_amdgcn_mfma_f32_16x16x32_bf16(ah[mf], bl, acc[mf][nf], 0, 0, 0);
                    acc[mf][nf] = __builtin_amdgcn_mfma_f32_16x16x32_bf16(al[mf], bh, acc[mf][nf], 0, 0, 0);
                }
            }
        }
        // ---- chunk epilogue: d = cn - 2*dot, running min ----
        #pragma unroll
        for (int nf = 0; nf < 8; ++nf) {
            int code = code0 + wn * 128 + nf * 16 + (l & 15);
            float cnv = cn[code];
            #pragma unroll
            for (int mf = 0; mf < 4; ++mf)
                #pragma unroll
                for (int rg = 0; rg < 4; ++rg) {
                    float d = fmaf(-2.f, acc[mf][nf][rg], cnv);
                    if (d < runv[mf][rg]) { runv[mf][rg] = d; runi[mf][rg] = code; }
                }
        }
    }
    // ---- final: top-2 across the 16 col-lanes, write candidates ----
    #pragma unroll
    for (int mf = 0; mf < 4; ++mf)
        #pragma unroll
        for (int rg = 0; rg < 4; ++rg) {
            float v1 = runv[mf][rg], v2 = INFINITY;
            int i1 = runi[mf][rg], i2 = 0x7fffffff;
            #pragma unroll
            for (int off = 8; off >= 1; off >>= 1) {
                float w1 = __shfl_xor(v1, off, 64), w2 = __shfl_xor(v2, off, 64);
                int j1 = __shfl_xor(i1, off, 64), j2 = __shfl_xor(i2, off, 64);
                top2_merge(v1, i1, v2, i2, w1, j1, w2, j2);
            }
            if ((l & 15) == 0) {
                int row = row0 + wm * 64 + mf * 16 + (l >> 4) * 4 + rg;
                cand[(size_t)row * 16 + g * 2 + wn] =
                    make_float4(v1, __int_as_float(i1), v2, __int_as_float(i2));
            }
        }
}

// ---------------- exact fp64 rescore of global approx-top-2 ----------------
__global__ __launch_bounds__(256) void rescore_kernel(const float4* __restrict__ cand,
                                                      const float* __restrict__ X,
                                                      const float* __restrict__ CB,
                                                      int* __restrict__ idx,
                                                      float* __restrict__ encOut) {
    int w = threadIdx.x >> 6, l = threadIdx.x & 63;
    int r = blockIdx.x * 4 + w;
    float v1, v2; int i1, i2;
    if (l < 16) {
        float4 c = cand[(size_t)r * 16 + l];
        v1 = c.x; i1 = __float_as_int(c.y); v2 = c.z; i2 = __float_as_int(c.w);
    } else { v1 = INFINITY; v2 = INFINITY; i1 = 0x7fffffff; i2 = 0x7fffffff; }
    #pragma unroll
    for (int off = 8; off >= 1; off >>= 1) {
        float w1 = __shfl_xor(v1, off, 64), w2 = __shfl_xor(v2, off, 64);
        int j1 = __shfl_xor(i1, off, 64), j2 = __shfl_xor(i2, off, 64);
        top2_merge(v1, i1, v2, i2, w1, j1, w2, j2);
    }
    int k1 = __shfl(i1, 0, 64), k2 = __shfl(i2, 0, 64);
    double d1 = 0, d2 = 0, n1 = 0, n2 = 0;
    #pragma unroll
    for (int j = 0; j < 12; ++j) {
        int c = l * 12 + j;
        double x = (double)X[(size_t)r * C_ + c];
        double a = (double)CB[(size_t)k1 * C_ + c];
        double b = (double)CB[(size_t)k2 * C_ + c];
        d1 += x * a; d2 += x * b; n1 += a * a; n2 += b * b;
    }
    #pragma unroll
    for (int off = 32; off >= 1; off >>= 1) {
        d1 += __shfl_xor(d1, off, 64); d2 += __shfl_xor(d2, off, 64);
        n1 += __shfl_xor(n1, off, 64); n2 += __shfl_xor(n2, off, 64);
    }
    if (l == 0) {
        double dd1 = n1 - 2.0 * d1, dd2 = n2 - 2.0 * d2;
        int kw = (dd2 < dd1 || (dd2 == dd1 && k2 < k1)) ? k2 : k1;
        idx[r] = kw;
        encOut[r] = (float)kw;
    }
}

// ---------------- generic split-bf16 conv GEMM: out[12544][NF*16] ------------
// A frag-linear [rg][kb24][l][e]; B frag-linear [cb(NF)][kb24][l][e]
template<int NF>
__global__ __launch_bounds__(256) void convgemm_kernel(const ushort_t* __restrict__ Ahi_g,
                                                       const ushort_t* __restrict__ Alo_g,
                                                       const ushort_t* __restrict__ Bhi_g,
                                                       const ushort_t* __restrict__ Blo_g,
                                                       float* __restrict__ out) {
    __shared__ __align__(16) ushort_t AhL[16 * 512];       // 8 rb x 2 kb
    __shared__ __align__(16) ushort_t AlL[16 * 512];
    __shared__ __align__(16) ushort_t BhL[NF * 2 * 512];
    __shared__ __align__(16) ushort_t BlL[NF * 2 * 512];
    const int tid = threadIdx.x;
    const int l = tid & 63, w = tid >> 6;
    const int rg0 = blockIdx.x * 8;
    const int row0 = blockIdx.x * 128;
    const int PW = 8 + NF;                                 // staging instrs per wave

    f32x4 acc[2][NF];
    #pragma unroll
    for (int mf = 0; mf < 2; ++mf)
        #pragma unroll
        for (int nf = 0; nf < NF; ++nf) acc[mf][nf] = (f32x4){0.f, 0.f, 0.f, 0.f};

    #pragma unroll 1
    for (int st = 0; st < 12; ++st) {
        __syncthreads();
        #pragma unroll
        for (int i = 0; i < PW; ++i) {
            int s = w * PW + i;
            if (s < 16) {                                  // A hi
                int rb = s >> 1, kb = s & 1;
                size_t goff = (((size_t)(rg0 + rb) * 24 + st * 2 + kb) << 9) + l * 8;
                gload_lds16(&Ahi_g[goff], &AhL[s << 9]);
            } else if (s < 32) {                           // A lo
                int t2 = s - 16;
                int rb = t2 >> 1, kb = t2 & 1;
                size_t goff = (((size_t)(rg0 + rb) * 24 + st * 2 + kb) << 9) + l * 8;
                gload_lds16(&Alo_g[goff], &AlL[t2 << 9]);
            } else if (s < 32 + 2 * NF) {                  // B hi
                int t2 = s - 32;
                int cb = t2 >> 1, kb = t2 & 1;
                size_t goff = (((size_t)cb * 24 + st * 2 + kb) << 9) + l * 8;
                gload_lds16(&Bhi_g[goff], &BhL[t2 << 9]);
            } else {                                       // B lo
                int t2 = s - 32 - 2 * NF;
                int cb = t2 >> 1, kb = t2 & 1;
                size_t goff = (((size_t)cb * 24 + st * 2 + kb) << 9) + l * 8;
                gload_lds16(&Blo_g[goff], &BlL[t2 << 9]);
            }
        }
        __syncthreads();
        #pragma unroll
        for (int kf = 0; kf < 2; ++kf) {
            short8v ah[2], al[2];
            #pragma unroll
            for (int mf = 0; mf < 2; ++mf) {
                int off = (((w * 2 + mf) * 2 + kf) << 9) + l * 8;
                ah[mf] = *(const short8v*)&AhL[off];
                al[mf] = *(const short8v*)&AlL[off];
            }
            #pragma unroll
            for (int nf = 0; nf < NF; ++nf) {
                int off = (((nf * 2) + kf) << 9) + l * 8;
                short8v bh = *(const short8v*)&BhL[off];
                short8v bl = *(const short8v*)&BlL[off];
                #pragma unroll
                for (int mf = 0; mf < 2; ++mf) {
                    acc[mf][nf] = __builtin_amdgcn_mfma_f32_16x16x32_bf16(ah[mf], bh, acc[mf][nf], 0, 0, 0);
                    acc[mf][nf] = __builtin_amdgcn_mfma_f32_16x16x32_bf16(ah[mf], bl, acc[mf][nf], 0, 0, 0);
                    acc[mf][nf] = __builtin_amdgcn_mfma_f32_16x16x32_bf16(al[mf], bh, acc[mf][nf], 0, 0, 0);
                }
            }
        }
    }
    #pragma unroll
    for (int mf = 0; mf < 2; ++mf)
        #pragma unroll
        for (int nf = 0; nf < NF; ++nf)
            #pragma unroll
            for (int rg = 0; rg < 4; ++rg) {
                int row = row0 + w * 32 + mf * 16 + (l >> 4) * 4 + rg;
                out[(size_t)row * (NF * 16) + nf * 16 + (l & 15)] = acc[mf][nf][rg];
            }
}

// ---------------- mm finish: shifted-add + frame diff + softmax ----------------
__global__ __launch_bounds__(256) void mm_finish_kernel(const float* __restrict__ XW,
                                                        const float* __restrict__ ex_b,
                                                        float* __restrict__ sm) {
    int b = blockIdx.x, t = threadIdx.x;
    float val = -INFINITY;
    if (t < L_) {
        if ((b & 3) == 0) val = ex_b[0];
        else {
            int yy = t / HW_, xx = t - (t / HW_) * HW_;
            float acc = 0.f;
            #pragma unroll
            for (int dy = 0; dy < 3; ++dy) {
                int sy = yy + dy - 1; if (sy < 0 || sy >= HW_) continue;
                #pragma unroll
                for (int dx = 0; dx < 3; ++dx) {
                    int sx = xx + dx - 1; if (sx < 0 || sx >= HW_) continue;
                    int q = sy * HW_ + sx, tap = dy * 3 + dx;
                    acc += XW[((size_t)b * L_ + q) * 16 + tap]
                         - XW[((size_t)(b - 1) * L_ + q) * 16 + tap];
                }
            }
            val = acc + ex_b[0];
        }
    }
    __shared__ float red[4];
    float mw = wave_reduce_max(val);
    if ((t & 63) == 0) red[t >> 6] = mw;
    __syncthreads();
    float mx = fmaxf(fmaxf(red[0], red[1]), fmaxf(red[2], red[3]));
    float e = (t < L_) ? expf(val - mx) : 0.f;
    __syncthreads();
    float sw = wave_reduce_sum(e);
    if ((t & 63) == 0) red[t >> 6] = sw;
    __syncthreads();
    float s = red[0] + red[1] + red[2] + red[3];
    if (t < L_) sm[b * L_ + t] = e / s;
}

// ---------------- vqf split: Vhi/Vlo = split(codebook[idx] + x*sm) ----------
// writes fragment-linear [rg][kb24][l][e]
__global__ __launch_bounds__(256) void vqf_split_kernel(const float* __restrict__ X,
                                                        const float* __restrict__ CB,
                                                        const int* __restrict__ idx,
                                                        const float* __restrict__ sm,
                                                        ushort_t* __restrict__ Vhi,
                                                        ushort_t* __restrict__ Vlo) {
    const int rg = blockIdx.x, t = threadIdx.x;
    #pragma unroll
    for (int i = 0; i < 6; ++i) {
        int s = t + i * 256;                       // 1536 slots
        int kb = s >> 6, l = s & 63;
        int row = rg * 16 + (l & 15);
        int k = kb * 32 + ((l >> 4) << 3);
        int kidx = idx[row];
        float sc = sm[row];
        const float* xp = &X[(size_t)row * C_ + k];
        const float* cp = &CB[(size_t)kidx * C_ + k];
        union { ushort_t u[8]; short8v v; } H, Lo;
        #pragma unroll
        for (int e = 0; e < 8; ++e) {
            float f = cp[e] + xp[e] * sc;
            ushort_t h = f2bf_rne(f);
            H.u[e] = h; Lo.u[e] = f2bf_rne(f - bf2f(h));
        }
        size_t goff = ((size_t)rg * 1536 + s) * 8;
        *(short8v*)&Vhi[goff] = H.v;
        *(short8v*)&Vlo[goff] = Lo.v;
    }
}

// ---------------- rm finish: shifted-add of OUTC + bias → region_mask --------
__global__ __launch_bounds__(256) void rm_finish_kernel(const float* __restrict__ OUTC,
                                                        const float* __restrict__ att_b,
                                                        float* __restrict__ rmOut) {
    int gid = blockIdx.x * 256 + threadIdx.x;      // 64*8*196 = 100352
    if (gid >= B_ * R_ * L_) return;
    int b = gid / (R_ * L_);
    int rem = gid - b * (R_ * L_);
    int r = rem / L_, p = rem - r * L_;
    int yy = p / HW_, xx = p - yy * HW_;
    float acc = att_b[r];
    #pragma unroll
    for (int dy = 0; dy < 3; ++dy) {
        int sy = yy + dy - 1; if (sy < 0 || sy >= HW_) continue;
        #pragma unroll
        for (int dx = 0; dx < 3; ++dx) {
            int sx = xx + dx - 1; if (sx < 0 || sx >= HW_) continue;
            int q = sy * HW_ + sx, tap = dy * 3 + dx;
            acc += OUTC[((size_t)b * L_ + q) * 80 + tap * 8 + r];
        }
    }
    rmOut[gid] = acc;
}

// ---------------- regions einsum from V splits ----------------
__global__ __launch_bounds__(256) void regions_kernel(const ushort_t* __restrict__ Vhi,
                                                      const ushort_t* __restrict__ Vlo,
                                                      const float* __restrict__ rm,
                                                      float* __restrict__ seq) {
    int b = blockIdx.x, t = threadIdx.x;
    __shared__ float rms[R_ * L_];
    for (int i = t; i < R_ * L_; i += 256) rms[i] = rm[(size_t)b * R_ * L_ + i];
    __syncthreads();
    const float inv = 1.f / 196.f;
    #pragma unroll
    for (int ci = 0; ci < 3; ++ci) {
        int c = t + ci * 256;
        int kb = c >> 5, q = (c >> 3) & 3, e = c & 7;
        float acc[R_] = {};
        for (int p = 0; p < L_; ++p) {
            int row = b * L_ + p;
            int rg = row >> 4, rr = row & 15;
            size_t a = ((((size_t)rg * 24 + kb) * 64) + q * 16 + rr) * 8 + e;
            float x = bf2f(Vhi[a]) + bf2f(Vlo[a]);
            #pragma unroll
            for (int r = 0; r < R_; ++r) acc[r] += x * rms[r * L_ + p];
        }
        #pragma unroll
        for (int r = 0; r < R_; ++r) seq[((size_t)b * R_ + r) * C_ + c] = acc[r] * inv;
    }
}

// ---------------- generic fp32 GEMM: out = A @ W^T + bias ----------------
__global__ __launch_bounds__(256) void gemm_bias_kernel(const float* __restrict__ A,
                                                        const float* __restrict__ Wt,
                                                        const float* __restrict__ bias,
                                                        float* __restrict__ out,
                                                        int M, int N, int K) {
    __shared__ __align__(16) float As[64][36];
    __shared__ __align__(16) float Bs[64][36];
    const int tid = threadIdx.x;
    const int tx = tid & 15, ty = tid >> 4;
    const int m0 = blockIdx.x * 64, n0 = blockIdx.y * 64;
    const int rl = tid >> 3, ql = (tid & 7) * 4;
    float acc[4][4] = {{0.f}};
    #pragma unroll 1
    for (int k0 = 0; k0 < K; k0 += 32) {
        __syncthreads();
        *(float4*)&As[rl][ql]      = *(const float4*)&A[(size_t)(m0 + rl) * K + k0 + ql];
        *(float4*)&As[rl + 32][ql] = *(const float4*)&A[(size_t)(m0 + rl + 32) * K + k0 + ql];
        *(float4*)&Bs[rl][ql]      = *(const float4*)&Wt[(size_t)(n0 + rl) * K + k0 + ql];
        *(float4*)&Bs[rl + 32][ql] = *(const float4*)&Wt[(size_t)(n0 + rl + 32) * K + k0 + ql];
        __syncthreads();
        #pragma unroll
        for (int kk = 0; kk < 32; kk += 4) {
            float4 a[4], bv[4];
            #pragma unroll
            for (int i = 0; i < 4; ++i) a[i]  = *(const float4*)&As[ty + 16 * i][kk];
            #pragma unroll
            for (int j = 0; j < 4; ++j) bv[j] = *(const float4*)&Bs[tx + 16 * j][kk];
            #pragma unroll
            for (int i = 0; i < 4; ++i)
                #pragma unroll
                for (int j = 0; j < 4; ++j)
                    acc[i][j] += a[i].x * bv[j].x + a[i].y * bv[j].y +
                                 a[i].z * bv[j].z + a[i].w * bv[j].w;
        }
    }
    #pragma unroll
    for (int i = 0; i < 4; ++i) {
        int row = m0 + ty + 16 * i;
        #pragma unroll
        for (int j = 0; j < 4; ++j) {
            int col = n0 + tx + 16 * j;
            out[(size_t)row * N + col] = acc[i][j] + bias[col];
        }
    }
}

// ---------------- per-(batch,head) attention over 32 tokens ----------------
__global__ __launch_bounds__(256) void attn_kernel(const float* __restrict__ qkv,
                                                   float* __restrict__ outb) {
    int bp = blockIdx.x, h = blockIdx.y;
    __shared__ float qs[NT_][DH_], ks[NT_][DH_], vs[NT_][DH_];
    __shared__ float sc[NT_][NT_ + 1];
    int tid = threadIdx.x;
    for (int e = tid; e < NT_ * DH_; e += 256) {
        int n = e / DH_, d = e - n * DH_;
        size_t base = ((size_t)(bp * NT_ + n)) * 2304 + h * DH_ + d;
        qs[n][d] = qkv[base];
        ks[n][d] = qkv[base + 768];
        vs[n][d] = qkv[base + 1536];
    }
    __syncthreads();
    const float scale = 1.0f / sqrtf((float)DH_);
    for (int e = tid; e < NT_ * NT_; e += 256) {
        int n = e >> 5, m = e & 31;
        float s = 0.f;
        #pragma unroll 8
        for (int d = 0; d < DH_; ++d) s += qs[n][d] * ks[m][d];
        sc[n][m] = s * scale;
    }
    __syncthreads();
    if (tid < NT_) {
        float mx = -INFINITY;
        #pragma unroll
        for (int m = 0; m < NT_; ++m) mx = fmaxf(mx, sc[tid][m]);
        float sum = 0.f;
        #pragma unroll
        for (int m = 0; m < NT_; ++m) { float e2 = expf(sc[tid][m] - mx); sc[tid][m] = e2; sum += e2; }
        float inv = 1.f / sum;
        #pragma unroll
        for (int m = 0; m < NT_; ++m) sc[tid][m] *= inv;
    }
    __syncthreads();
    for (int e = tid; e < NT_ * DH_; e += 256) {
        int n = e / DH_, d = e - n * DH_;
        float o = 0.f;
        #pragma unroll
        for (int m = 0; m < NT_; ++m) o += sc[n][m] * vs[m][d];
        outb[((size_t)(bp * NT_ + n)) * C_ + h * DH_ + d] = o;
    }
}

// ---------------- launch ----------------
extern "C" void kernel_launch(void* const* d_in, const int* in_sizes, int n_in,
                              void* d_out, int out_size, void* d_ws, size_t ws_size,
                              hipStream_t stream) {
    const float* in_feas  = (const float*)d_in[0];
    const float* codebook = (const float*)d_in[2];
    const float* att_w    = (const float*)d_in[3];
    const float* att_b    = (const float*)d_in[4];
    const float* ex_w     = (const float*)d_in[5];
    const float* ex_b     = (const float*)d_in[6];
    const float* qkv_w    = (const float*)d_in[7];
    const float* qkv_b    = (const float*)d_in[8];
    const float* proj_w   = (const float*)d_in[9];
    const float* proj_b   = (const float*)d_in[10];

    float* out    = (float*)d_out;
    float* outVd  = out;
    float* outEnc = out + 393216;
    float* outRm  = out + 393216 + 12544;

    float* ws = (float*)d_ws;
    // phase-1 buffers
    float*    cn   = ws + 0;                           // 8,192
    float4*   cand = (float4*)(ws + 8192);             // 802,816 fl
    ushort_t* CBhi = (ushort_t*)(ws + 811008);         // 3,145,728 fl
    ushort_t* CBlo = (ushort_t*)(ws + 3956736);
    ushort_t* Ahi  = (ushort_t*)(ws + 7102464);        // 4,816,896 fl
    ushort_t* Alo  = (ushort_t*)(ws + 11919360);       // ends 16,736,256
    // tail (no overlap)
    int*      idx   = (int*)(ws + 16736256);           // 12,544
    float*    XW    = ws + 16748800;                   // 200,704 (live steps 5->8)
    ushort_t* attHi = (ushort_t*)(ws + 16949504);      // 15,360 fl each
    ushort_t* attLo = (ushort_t*)(ws + 16964864);
    ushort_t* exHi  = (ushort_t*)(ws + 16980224);      // 3,072 fl each
    ushort_t* exLo  = (ushort_t*)(ws + 16983296);      // ends 16,986,368 (68 MB)
    // overlays: V splits over cand+CB splits+Ahi-head (all dead by step 9)
    ushort_t* Vhi  = (ushort_t*)(ws + 8192);           // 4,816,896 fl
    ushort_t* Vlo  = (ushort_t*)(ws + 8192 + 4816896); // ends 9,641,984
    // overlays in Alo region (Alo dead after convgemm<1>)
    float* OUTC  = ws + 11919360;                      // 1,003,520 -> 12,922,880
    float* sm    = ws + 13000000;                      // 12,544
    float* seq   = ws + 13100000;                      // 393,216
    float* qkvb  = ws + 13600000;                      // 1,179,648 -> 14,779,648
    float* attnb = ws + 14800000;                      // 393,216 -> 15,193,216

    hipLaunchKernelGGL(cnorm_kernel, dim3(K_), dim3(64), 0, stream, codebook, cn);
    hipLaunchKernelGGL(cb_split_kernel, dim3(3072), dim3(256), 0, stream, codebook, CBhi, CBlo);
    hipLaunchKernelGGL(a_split_kernel, dim3(784), dim3(256), 0, stream, in_feas, Ahi, Alo);
    hipLaunchKernelGGL(wsplit_kernel, dim3(36), dim3(256), 0, stream,
                       att_w, ex_w, attHi, attLo, exHi, exLo);
    hipLaunchKernelGGL(vq_mfma_kernel, dim3(8, 98), dim3(256), 0, stream,
                       Ahi, Alo, CBhi, CBlo, cn, cand);
    hipLaunchKernelGGL((convgemm_kernel<1>), dim3(98), dim3(256), 0, stream,
                       Ahi, Alo, exHi, exLo, XW);
    hipLaunchKernelGGL(rescore_kernel, dim3(M_ / 4), dim3(256), 0, stream,
                       cand, in_feas, codebook, idx, outEnc);
    hipLaunchKernelGGL(mm_finish_kernel, dim3(B_), dim3(256), 0, stream, XW, ex_b, sm);
    hipLaunchKernelGGL(vqf_split_kernel, dim3(784), dim3(256), 0, stream,
                       in_feas, codebook, idx, sm, Vhi, Vlo);
    hipLaunchKernelGGL((convgemm_kernel<5>), dim3(98), dim3(256), 0, stream,
                       Vhi, Vlo, attHi, attLo, OUTC);
    hipLaunchKernelGGL(rm_finish_kernel, dim3(392), dim3(256), 0, stream,
                       OUTC, att_b, outRm);
    hipLaunchKernelGGL(regions_kernel, dim3(B_), dim3(256), 0, stream,
                       Vhi, Vlo, outRm, seq);
    hipLaunchKernelGGL(gemm_bias_kernel, dim3(8, 36), dim3(256), 0, stream,
                       seq, qkv_w, qkv_b, qkvb, 512, 2304, 768);
    hipLaunchKernelGGL(attn_kernel, dim3(BP_, NH_), dim3(256), 0, stream, qkvb, attnb);
    hipLaunchKernelGGL(gemm_bias_kernel, dim3(8, 12), dim3(256), 0, stream,
                       attnb, proj_w, proj_b, outVd, 512, 768, 768);
}

// Round 6
// 548.265 us; speedup vs baseline: 7.1274x; 1.4718x over previous
//
#include <hip/hip_runtime.h>
#include <math.h>

#define B_   64
#define L_   196
#define C_   768
#define K_   8192
#define R_   8
#define HW_  14
#define M_   (B_*L_)     // 12544
#define NH_  8
#define DH_  96
#define BP_  16
#define NT_  32

typedef unsigned short ushort_t;
typedef __attribute__((ext_vector_type(8))) short short8v;   // 8 bf16 (4 VGPR)
typedef __attribute__((ext_vector_type(4))) float f32x4;     // MFMA 16x16 acc

// ---------------- utilities ----------------
__device__ inline float wave_reduce_sum(float v) {
    #pragma unroll
    for (int o = 32; o >= 1; o >>= 1) v += __shfl_xor(v, o, 64);
    return v;
}
__device__ inline float wave_reduce_max(float v) {
    #pragma unroll
    for (int o = 32; o >= 1; o >>= 1) v = fmaxf(v, __shfl_xor(v, o, 64));
    return v;
}

__device__ inline ushort_t f2bf_rne(float f) {
    unsigned u = __float_as_uint(f);
    unsigned r = u + 0x7fffu + ((u >> 16) & 1u);
    return (ushort_t)(r >> 16);
}
__device__ inline float bf2f(ushort_t h) { return __uint_as_float(((unsigned)h) << 16); }

__device__ inline void gload_lds16(const void* gsrc, void* ldst) {
    __builtin_amdgcn_global_load_lds(
        (const __attribute__((address_space(1))) unsigned int*)gsrc,
        (__attribute__((address_space(3))) unsigned int*)ldst, 16, 0, 0);
}

// merge two sorted pairs -> sorted top-2 of union (lowest-index tie-break)
__device__ inline void top2_merge(float& v1, int& i1, float& v2, int& i2,
                                  float w1, int j1, float w2, int j2) {
    bool fw = (v1 < w1) || (v1 == w1 && i1 <= j1);
    float a1 = fw ? v1 : w1;  int ai1 = fw ? i1 : j1;
    float lb = fw ? w1 : v1;  int lbi = fw ? j1 : i1;
    float wsv = fw ? v2 : w2; int wsi = fw ? i2 : j2;
    bool sb = (lb < wsv) || (lb == wsv && lbi < wsi);
    v1 = a1; i1 = ai1;
    v2 = sb ? lb : wsv; i2 = sb ? lbi : wsi;
}

__device__ inline void ce4(float& v0, int& j0, float& v1, int& j1) {
    bool sw = (v1 < v0) || (v1 == v0 && j1 < j0);
    float tv = sw ? v1 : v0, uv = sw ? v0 : v1;
    int tj = sw ? j1 : j0, uj = sw ? j0 : j1;
    v0 = tv; j0 = tj; v1 = uv; j1 = uj;
}
__device__ inline void pickmin(float& v, int& j, float bv, int bj) {
    if (bv < v || (bv == v && bj < j)) { v = bv; j = bj; }
}

// ---------------- codebook norms ----------------
__global__ __launch_bounds__(64) void cnorm_kernel(const float* __restrict__ cb,
                                                   float* __restrict__ cn) {
    int k = blockIdx.x;
    const float* row = cb + (size_t)k * C_;
    float s = 0.f;
    for (int c = threadIdx.x; c < C_; c += 64) { float v = row[c]; s += v * v; }
    s = wave_reduce_sum(s);
    if (threadIdx.x == 0) cn[k] = s;
}

// ---------------- codebook -> fragment-linear bf16 (hi only) ----------------
// layout: [cb_g(512)][kb_g(24)][lane(64)][e(8)]; code = cb_g*16+(l&15), k = kb_g*32+(l>>4)*8+e
__global__ __launch_bounds__(256) void cb_split_kernel(const float* __restrict__ CB,
                                                       ushort_t* __restrict__ CBhi) {
    int s = blockIdx.x * 256 + threadIdx.x;      // 786432 slots
    int cb_g = s / 1536;
    int rem = s - cb_g * 1536;
    int kb_g = rem >> 6, l = rem & 63;
    int code = (cb_g << 4) + (l & 15);
    int k = kb_g * 32 + (l >> 4) * 8;
    const float* gp = CB + (size_t)code * C_ + k;
    union { ushort_t u[8]; short8v v; } H;
    #pragma unroll
    for (int e = 0; e < 8; ++e) H.u[e] = f2bf_rne(gp[e]);
    *(short8v*)&CBhi[(size_t)s * 8] = H.v;
}

// ---------------- A -> fragment-linear bf16 (hi only) ----------------
__global__ __launch_bounds__(256) void a_split_kernel(const float* __restrict__ X,
                                                      ushort_t* __restrict__ Ahi) {
    __shared__ float xs[16 * 776];
    const int t = threadIdx.x;
    const int rg = blockIdx.x;
    const float4* src = (const float4*)(X + (size_t)rg * 16 * C_);
    #pragma unroll
    for (int i = 0; i < 12; ++i) {
        int idx4 = t + i * 256;
        int r = idx4 / 192, c4 = idx4 - r * 192;
        ((float4*)(xs + r * 776))[c4] = src[idx4];
    }
    __syncthreads();
    #pragma unroll
    for (int i = 0; i < 6; ++i) {
        int s = t + i * 256;
        int kb = s >> 6, l = s & 63;
        int r = l & 15;
        int k = kb * 32 + (l >> 4) * 8;
        const float* xp = &xs[r * 776 + k];
        union { ushort_t u[8]; short8v v; } H;
        #pragma unroll
        for (int e = 0; e < 8; ++e) H.u[e] = f2bf_rne(xp[e]);
        *(short8v*)&Ahi[((size_t)rg * 1536 + s) * 8] = H.v;
    }
}

// ---------------- conv weight -> fragment-linear bf16 (hi only) -------------
__global__ __launch_bounds__(256) void wsplit_kernel(const float* __restrict__ att_w,
                                                     const float* __restrict__ ex_w,
                                                     ushort_t* __restrict__ attHi,
                                                     ushort_t* __restrict__ exHi) {
    int gid = blockIdx.x * 256 + threadIdx.x;
    if (gid >= 9216) return;
    union { ushort_t u[8]; short8v v; } H;
    if (gid < 7680) {                                  // att: 5*24*64 slots
        int cb = gid / 1536;
        int rem = gid - cb * 1536;
        int l = rem & 63;
        int col = cb * 16 + (l & 15);
        int k = ((rem >> 6) << 5) + ((l >> 4) << 3);
        #pragma unroll
        for (int e = 0; e < 8; ++e) {
            int c = k + e;
            float f = (col < 72) ? att_w[(size_t)(col & 7) * 6912 + c * 9 + (col >> 3)] : 0.f;
            H.u[e] = f2bf_rne(f);
        }
        *(short8v*)&attHi[(size_t)gid * 8] = H.v;
    } else {                                           // ex: 1*24*64 slots
        int g2 = gid - 7680;
        int l = g2 & 63;
        int col = l & 15;
        int k = ((g2 >> 6) << 5) + ((l >> 4) << 3);
        #pragma unroll
        for (int e = 0; e < 8; ++e) {
            int c = k + e;
            float f = (col < 9) ? ex_w[c * 9 + col] : 0.f;
            H.u[e] = f2bf_rne(f);
        }
        *(short8v*)&exHi[(size_t)g2 * 8] = H.v;
    }
}

// ---------------- VQ: single-pass bf16 MFMA, BM=64 BN=512 BK=64 -------------
// grid (8, 196): g = code split (1024 codes, XCD-pinned), mt = 64-row tile
// per-lane running top-2 per row; cross-lane exact top-2 per (g,w) 256-code subset
__global__ __launch_bounds__(256, 2) void vq_mfma_kernel(const ushort_t* __restrict__ Ahi_g,
                                                         const ushort_t* __restrict__ CBhi,
                                                         const float* __restrict__ cn,
                                                         float4* __restrict__ cand) {
    __shared__ __align__(16) ushort_t AhL[8 * 512];    // 8 KB
    __shared__ __align__(16) ushort_t BhL[64 * 512];   // 64 KB

    const int tid = threadIdx.x;
    const int l = tid & 63, w = tid >> 6;              // w = col quadrant 0..3
    const int g = blockIdx.x;
    const int mt = blockIdx.y;
    const int row0 = mt * 64;
    const int rg0 = mt * 4;

    float v1[4][4], v2[4][4]; int i1[4][4], i2[4][4];
    #pragma unroll
    for (int mf = 0; mf < 4; ++mf)
        #pragma unroll
        for (int rg = 0; rg < 4; ++rg) {
            v1[mf][rg] = INFINITY; v2[mf][rg] = INFINITY;
            i1[mf][rg] = 0x7fffffff; i2[mf][rg] = 0x7fffffff;
        }

    #pragma unroll 1
    for (int ch = 0; ch < 2; ++ch) {
        const int cbase = g * 64 + ch * 32;
        f32x4 acc[4][8];
        #pragma unroll
        for (int mf = 0; mf < 4; ++mf)
            #pragma unroll
            for (int nf = 0; nf < 8; ++nf) acc[mf][nf] = (f32x4){0.f, 0.f, 0.f, 0.f};

        #pragma unroll 1
        for (int st = 0; st < 12; ++st) {
            __syncthreads();
            // stage 72 1KB subtiles: A 8 (4 rg x 2 kb) + B 64 (32 cb x 2 kb)
            #pragma unroll
            for (int i = 0; i < 18; ++i) {
                int s = w * 18 + i;
                if (s < 8) {
                    size_t goff = (((size_t)(rg0 + (s >> 1)) * 24 + st * 2 + (s & 1)) << 9) + l * 8;
                    gload_lds16(&Ahi_g[goff], &AhL[s << 9]);
                } else {
                    int s2 = s - 8;
                    size_t goff = (((size_t)(cbase + (s2 >> 1)) * 24 + st * 2 + (s2 & 1)) << 9) + l * 8;
                    gload_lds16(&CBhi[goff], &BhL[s2 << 9]);
                }
            }
            __syncthreads();
            #pragma unroll
            for (int kf = 0; kf < 2; ++kf) {
                short8v ah[4];
                #pragma unroll
                for (int mf = 0; mf < 4; ++mf)
                    ah[mf] = *(const short8v*)&AhL[((mf * 2 + kf) << 9) + l * 8];
                #pragma unroll
                for (int nf = 0; nf < 8; ++nf) {
                    int cb = w * 8 + nf;
                    short8v bh = *(const short8v*)&BhL[((cb * 2 + kf) << 9) + l * 8];
                    #pragma unroll
                    for (int mf = 0; mf < 4; ++mf)
                        acc[mf][nf] = __builtin_amdgcn_mfma_f32_16x16x32_bf16(ah[mf], bh, acc[mf][nf], 0, 0, 0);
                }
            }
        }
        // chunk epilogue: d = cn - 2*dot; per-lane top-2 insert per row
        #pragma unroll
        for (int nf = 0; nf < 8; ++nf) {
            int code = g * 1024 + ch * 512 + w * 128 + nf * 16 + (l & 15);
            float cnv = cn[code];
            #pragma unroll
            for (int mf = 0; mf < 4; ++mf)
                #pragma unroll
                for (int rg = 0; rg < 4; ++rg) {
                    float d = fmaf(-2.f, acc[mf][nf][rg], cnv);
                    bool c1 = d < v1[mf][rg];
                    bool c2 = d < v2[mf][rg];
                    float nv2 = c1 ? v1[mf][rg] : (c2 ? d : v2[mf][rg]);
                    int   ni2 = c1 ? i1[mf][rg] : (c2 ? code : i2[mf][rg]);
                    v2[mf][rg] = nv2; i2[mf][rg] = ni2;
                    if (c1) { v1[mf][rg] = d; i1[mf][rg] = code; }
                }
        }
    }
    // cross-lane exact top-2 per row over the 16 col-lanes; write subset pair
    #pragma unroll
    for (int mf = 0; mf < 4; ++mf)
        #pragma unroll
        for (int rg = 0; rg < 4; ++rg) {
            float a1 = v1[mf][rg], a2 = v2[mf][rg];
            int b1 = i1[mf][rg], b2 = i2[mf][rg];
            #pragma unroll
            for (int off = 8; off >= 1; off >>= 1) {
                float w1 = __shfl_xor(a1, off, 64), w2 = __shfl_xor(a2, off, 64);
                int j1 = __shfl_xor(b1, off, 64), j2 = __shfl_xor(b2, off, 64);
                top2_merge(a1, b1, a2, b2, w1, j1, w2, j2);
            }
            if ((l & 15) == 0) {
                int row = row0 + mf * 16 + (l >> 4) * 4 + rg;
                cand[(size_t)row * 32 + g * 4 + w] =
                    make_float4(a1, __int_as_float(b1), a2, __int_as_float(b2));
            }
        }
}

// ---------------- rescore: exact top-4 of 32 subset-pairs, fp64 re-eval ------
__global__ __launch_bounds__(256) void rescore_kernel(const float4* __restrict__ cand,
                                                      const float* __restrict__ X,
                                                      const float* __restrict__ CB,
                                                      int* __restrict__ idx,
                                                      float* __restrict__ encOut) {
    int w = threadIdx.x >> 6, l = threadIdx.x & 63;
    int r = blockIdx.x * 4 + w;
    float a0, a1, a2, a3; int j0, j1, j2, j3;
    if (l < 32) {
        float4 c = cand[(size_t)r * 32 + l];
        a0 = c.x; j0 = __float_as_int(c.y);
        a1 = c.z; j1 = __float_as_int(c.w);
    } else { a0 = INFINITY; a1 = INFINITY; j0 = 0x7fffffff; j1 = 0x7fffffff; }
    a2 = INFINITY; a3 = INFINITY; j2 = 0x7fffffff; j3 = 0x7fffffff;
    #pragma unroll
    for (int off = 32; off >= 1; off >>= 1) {
        float b0 = __shfl_xor(a0, off, 64), b1 = __shfl_xor(a1, off, 64);
        float b2 = __shfl_xor(a2, off, 64), b3 = __shfl_xor(a3, off, 64);
        int p0 = __shfl_xor(j0, off, 64), p1 = __shfl_xor(j1, off, 64);
        int p2 = __shfl_xor(j2, off, 64), p3 = __shfl_xor(j3, off, 64);
        // bitonic lower half of [a0..a3, b3..b0]
        pickmin(a0, j0, b3, p3); pickmin(a1, j1, b2, p2);
        pickmin(a2, j2, b1, p1); pickmin(a3, j3, b0, p0);
        // bitonic sort-4
        ce4(a0, j0, a2, j2); ce4(a1, j1, a3, j3);
        ce4(a0, j0, a1, j1); ce4(a2, j2, a3, j3);
    }
    // all lanes now hold the global sorted top-4 candidate indices j0..j3
    double dot0 = 0, dot1 = 0, dot2 = 0, dot3 = 0;
    double nn0 = 0, nn1 = 0, nn2 = 0, nn3 = 0;
    const float* xr = X + (size_t)r * C_;
    #pragma unroll
    for (int jj = 0; jj < 12; ++jj) {
        int c = l * 12 + jj;
        double x = (double)xr[c];
        double c0 = (double)CB[(size_t)j0 * C_ + c]; dot0 += x * c0; nn0 += c0 * c0;
        double c1 = (double)CB[(size_t)j1 * C_ + c]; dot1 += x * c1; nn1 += c1 * c1;
        double c2 = (double)CB[(size_t)j2 * C_ + c]; dot2 += x * c2; nn2 += c2 * c2;
        double c3 = (double)CB[(size_t)j3 * C_ + c]; dot3 += x * c3; nn3 += c3 * c3;
    }
    #pragma unroll
    for (int off = 32; off >= 1; off >>= 1) {
        dot0 += __shfl_xor(dot0, off, 64); dot1 += __shfl_xor(dot1, off, 64);
        dot2 += __shfl_xor(dot2, off, 64); dot3 += __shfl_xor(dot3, off, 64);
        nn0 += __shfl_xor(nn0, off, 64); nn1 += __shfl_xor(nn1, off, 64);
        nn2 += __shfl_xor(nn2, off, 64); nn3 += __shfl_xor(nn3, off, 64);
    }
    if (l == 0) {
        double d0 = nn0 - 2.0 * dot0, d1 = nn1 - 2.0 * dot1;
        double d2 = nn2 - 2.0 * dot2, d3 = nn3 - 2.0 * dot3;
        double best = d0; int bi = j0;
        if (d1 < best || (d1 == best && j1 < bi)) { best = d1; bi = j1; }
        if (d2 < best || (d2 == best && j2 < bi)) { best = d2; bi = j2; }
        if (d3 < best || (d3 == best && j3 < bi)) { best = d3; bi = j3; }
        idx[r] = bi;
        encOut[r] = (float)bi;
    }
}

// ---------------- single-pass bf16 conv GEMM: out[12544][NF*16] -------------
template<int NF>
__global__ __launch_bounds__(256) void convgemm_kernel(const ushort_t* __restrict__ Ahi_g,
                                                       const ushort_t* __restrict__ Bhi_g,
                                                       float* __restrict__ out) {
    __shared__ __align__(16) ushort_t AhL[16 * 512];       // 8 rb x 2 kb
    __shared__ __align__(16) ushort_t BhL[NF * 2 * 512];
    const int TOT = 16 + 2 * NF;
    const int PW = (TOT + 3) >> 2;
    const int tid = threadIdx.x;
    const int l = tid & 63, w = tid >> 6;
    const int rg0 = blockIdx.x * 8;
    const int row0 = blockIdx.x * 128;

    f32x4 acc[2][NF];
    #pragma unroll
    for (int mf = 0; mf < 2; ++mf)
        #pragma unroll
        for (int nf = 0; nf < NF; ++nf) acc[mf][nf] = (f32x4){0.f, 0.f, 0.f, 0.f};

    #pragma unroll 1
    for (int st = 0; st < 12; ++st) {
        __syncthreads();
        #pragma unroll
        for (int i = 0; i < PW; ++i) {
            int s = w * PW + i;
            if (s < 16) {
                int rb = s >> 1, kb = s & 1;
                size_t goff = (((size_t)(rg0 + rb) * 24 + st * 2 + kb) << 9) + l * 8;
                gload_lds16(&Ahi_g[goff], &AhL[s << 9]);
            } else if (s < TOT) {
                int t2 = s - 16;
                int cb = t2 >> 1, kb = t2 & 1;
                size_t goff = (((size_t)cb * 24 + st * 2 + kb) << 9) + l * 8;
                gload_lds16(&Bhi_g[goff], &BhL[t2 << 9]);
            }
        }
        __syncthreads();
        #pragma unroll
        for (int kf = 0; kf < 2; ++kf) {
            short8v ah[2];
            #pragma unroll
            for (int mf = 0; mf < 2; ++mf)
                ah[mf] = *(const short8v*)&AhL[(((w * 2 + mf) * 2 + kf) << 9) + l * 8];
            #pragma unroll
            for (int nf = 0; nf < NF; ++nf) {
                short8v bh = *(const short8v*)&BhL[((nf * 2 + kf) << 9) + l * 8];
                #pragma unroll
                for (int mf = 0; mf < 2; ++mf)
                    acc[mf][nf] = __builtin_amdgcn_mfma_f32_16x16x32_bf16(ah[mf], bh, acc[mf][nf], 0, 0, 0);
            }
        }
    }
    #pragma unroll
    for (int mf = 0; mf < 2; ++mf)
        #pragma unroll
        for (int nf = 0; nf < NF; ++nf)
            #pragma unroll
            for (int rg = 0; rg < 4; ++rg) {
                int row = row0 + w * 32 + mf * 16 + (l >> 4) * 4 + rg;
                out[(size_t)row * (NF * 16) + nf * 16 + (l & 15)] = acc[mf][nf][rg];
            }
}

// ---------------- mm finish: shifted-add + frame diff + softmax --------------
__global__ __launch_bounds__(256) void mm_finish_kernel(const float* __restrict__ XW,
                                                        const float* __restrict__ ex_b,
                                                        float* __restrict__ sm) {
    int b = blockIdx.x, t = threadIdx.x;
    float val = -INFINITY;
    if (t < L_) {
        if ((b & 3) == 0) val = ex_b[0];
        else {
            int yy = t / HW_, xx = t - (t / HW_) * HW_;
            float acc = 0.f;
            #pragma unroll
            for (int dy = 0; dy < 3; ++dy) {
                int sy = yy + dy - 1; if (sy < 0 || sy >= HW_) continue;
                #pragma unroll
                for (int dx = 0; dx < 3; ++dx) {
                    int sx = xx + dx - 1; if (sx < 0 || sx >= HW_) continue;
                    int q = sy * HW_ + sx, tap = dy * 3 + dx;
                    acc += XW[((size_t)b * L_ + q) * 16 + tap]
                         - XW[((size_t)(b - 1) * L_ + q) * 16 + tap];
                }
            }
            val = acc + ex_b[0];
        }
    }
    __shared__ float red[4];
    float mw = wave_reduce_max(val);
    if ((t & 63) == 0) red[t >> 6] = mw;
    __syncthreads();
    float mx = fmaxf(fmaxf(red[0], red[1]), fmaxf(red[2], red[3]));
    float e = (t < L_) ? expf(val - mx) : 0.f;
    __syncthreads();
    float sw = wave_reduce_sum(e);
    if ((t & 63) == 0) red[t >> 6] = sw;
    __syncthreads();
    float s = red[0] + red[1] + red[2] + red[3];
    if (t < L_) sm[b * L_ + t] = e / s;
}

// ---------------- vqf -> fragment-linear bf16 (hi only) ----------------
__global__ __launch_bounds__(256) void vqf_split_kernel(const float* __restrict__ X,
                                                        const float* __restrict__ CB,
                                                        const int* __restrict__ idx,
                                                        const float* __restrict__ sm,
                                                        ushort_t* __restrict__ Vhi) {
    const int rg = blockIdx.x, t = threadIdx.x;
    #pragma unroll
    for (int i = 0; i < 6; ++i) {
        int s = t + i * 256;
        int kb = s >> 6, l = s & 63;
        int row = rg * 16 + (l & 15);
        int k = kb * 32 + ((l >> 4) << 3);
        int kidx = idx[row];
        float sc = sm[row];
        const float* xp = &X[(size_t)row * C_ + k];
        const float* cp = &CB[(size_t)kidx * C_ + k];
        union { ushort_t u[8]; short8v v; } H;
        #pragma unroll
        for (int e = 0; e < 8; ++e) H.u[e] = f2bf_rne(cp[e] + xp[e] * sc);
        *(short8v*)&Vhi[((size_t)rg * 1536 + s) * 8] = H.v;
    }
}

// ---------------- rm finish: shifted-add of OUTC + bias ----------------
__global__ __launch_bounds__(256) void rm_finish_kernel(const float* __restrict__ OUTC,
                                                        const float* __restrict__ att_b,
                                                        float* __restrict__ rmOut) {
    int gid = blockIdx.x * 256 + threadIdx.x;      // 100352
    if (gid >= B_ * R_ * L_) return;
    int b = gid / (R_ * L_);
    int rem = gid - b * (R_ * L_);
    int r = rem / L_, p = rem - r * L_;
    int yy = p / HW_, xx = p - yy * HW_;
    float acc = att_b[r];
    #pragma unroll
    for (int dy = 0; dy < 3; ++dy) {
        int sy = yy + dy - 1; if (sy < 0 || sy >= HW_) continue;
        #pragma unroll
        for (int dx = 0; dx < 3; ++dx) {
            int sx = xx + dx - 1; if (sx < 0 || sx >= HW_) continue;
            int q = sy * HW_ + sx, tap = dy * 3 + dx;
            acc += OUTC[((size_t)b * L_ + q) * 80 + tap * 8 + r];
        }
    }
    rmOut[gid] = acc;
}

// ---------------- regions einsum from Vhi ----------------
__global__ __launch_bounds__(256) void regions_kernel(const ushort_t* __restrict__ Vhi,
                                                      const float* __restrict__ rm,
                                                      float* __restrict__ seq) {
    int b = blockIdx.x, cg = blockIdx.y, t = threadIdx.x;
    __shared__ float rms[R_ * L_];
    for (int i = t; i < R_ * L_; i += 256) rms[i] = rm[(size_t)b * R_ * L_ + i];
    __syncthreads();
    const float inv = 1.f / 196.f;
    int c = cg * 256 + t;
    int kb = c >> 5, q = (c >> 3) & 3, e = c & 7;
    float acc[R_] = {};
    for (int p = 0; p < L_; ++p) {
        int row = b * L_ + p;
        int rg = row >> 4, rr = row & 15;
        size_t a = (((size_t)rg * 24 + kb) * 64 + q * 16 + rr) * 8 + e;
        float x = bf2f(Vhi[a]);
        #pragma unroll
        for (int r = 0; r < R_; ++r) acc[r] += x * rms[r * L_ + p];
    }
    #pragma unroll
    for (int r = 0; r < R_; ++r) seq[((size_t)b * R_ + r) * C_ + c] = acc[r] * inv;
}

// ---------------- generic fp32 GEMM: out = A @ W^T + bias ----------------
__global__ __launch_bounds__(256) void gemm_bias_kernel(const float* __restrict__ A,
                                                        const float* __restrict__ Wt,
                                                        const float* __restrict__ bias,
                                                        float* __restrict__ out,
                                                        int M, int N, int K) {
    __shared__ __align__(16) float As[64][36];
    __shared__ __align__(16) float Bs[64][36];
    const int tid = threadIdx.x;
    const int tx = tid & 15, ty = tid >> 4;
    const int m0 = blockIdx.x * 64, n0 = blockIdx.y * 64;
    const int rl = tid >> 3, ql = (tid & 7) * 4;
    float acc[4][4] = {{0.f}};
    #pragma unroll 1
    for (int k0 = 0; k0 < K; k0 += 32) {
        __syncthreads();
        *(float4*)&As[rl][ql]      = *(const float4*)&A[(size_t)(m0 + rl) * K + k0 + ql];
        *(float4*)&As[rl + 32][ql] = *(const float4*)&A[(size_t)(m0 + rl + 32) * K + k0 + ql];
        *(float4*)&Bs[rl][ql]      = *(const float4*)&Wt[(size_t)(n0 + rl) * K + k0 + ql];
        *(float4*)&Bs[rl + 32][ql] = *(const float4*)&Wt[(size_t)(n0 + rl + 32) * K + k0 + ql];
        __syncthreads();
        #pragma unroll
        for (int kk = 0; kk < 32; kk += 4) {
            float4 a[4], bv[4];
            #pragma unroll
            for (int i = 0; i < 4; ++i) a[i]  = *(const float4*)&As[ty + 16 * i][kk];
            #pragma unroll
            for (int j = 0; j < 4; ++j) bv[j] = *(const float4*)&Bs[tx + 16 * j][kk];
            #pragma unroll
            for (int i = 0; i < 4; ++i)
                #pragma unroll
                for (int j = 0; j < 4; ++j)
                    acc[i][j] += a[i].x * bv[j].x + a[i].y * bv[j].y +
                                 a[i].z * bv[j].z + a[i].w * bv[j].w;
        }
    }
    #pragma unroll
    for (int i = 0; i < 4; ++i) {
        int row = m0 + ty + 16 * i;
        #pragma unroll
        for (int j = 0; j < 4; ++j) {
            int col = n0 + tx + 16 * j;
            out[(size_t)row * N + col] = acc[i][j] + bias[col];
        }
    }
}

// ---------------- per-(batch,head) attention over 32 tokens ----------------
__global__ __launch_bounds__(256) void attn_kernel(const float* __restrict__ qkv,
                                                   float* __restrict__ outb) {
    int bp = blockIdx.x, h = blockIdx.y;
    __shared__ float qs[NT_][DH_], ks[NT_][DH_], vs[NT_][DH_];
    __shared__ float sc[NT_][NT_ + 1];
    int tid = threadIdx.x;
    for (int e = tid; e < NT_ * DH_; e += 256) {
        int n = e / DH_, d = e - n * DH_;
        size_t base = ((size_t)(bp * NT_ + n)) * 2304 + h * DH_ + d;
        qs[n][d] = qkv[base];
        ks[n][d] = qkv[base + 768];
        vs[n][d] = qkv[base + 1536];
    }
    __syncthreads();
    const float scale = 1.0f / sqrtf((float)DH_);
    for (int e = tid; e < NT_ * NT_; e += 256) {
        int n = e >> 5, m = e & 31;
        float s = 0.f;
        #pragma unroll 8
        for (int d = 0; d < DH_; ++d) s += qs[n][d] * ks[m][d];
        sc[n][m] = s * scale;
    }
    __syncthreads();
    if (tid < NT_) {
        float mx = -INFINITY;
        #pragma unroll
        for (int m = 0; m < NT_; ++m) mx = fmaxf(mx, sc[tid][m]);
        float sum = 0.f;
        #pragma unroll
        for (int m = 0; m < NT_; ++m) { float e2 = expf(sc[tid][m] - mx); sc[tid][m] = e2; sum += e2; }
        float inv = 1.f / sum;
        #pragma unroll
        for (int m = 0; m < NT_; ++m) sc[tid][m] *= inv;
    }
    __syncthreads();
    for (int e = tid; e < NT_ * DH_; e += 256) {
        int n = e / DH_, d = e - n * DH_;
        float o = 0.f;
        #pragma unroll
        for (int m = 0; m < NT_; ++m) o += sc[n][m] * vs[m][d];
        outb[((size_t)(bp * NT_ + n)) * C_ + h * DH_ + d] = o;
    }
}

// ---------------- launch ----------------
extern "C" void kernel_launch(void* const* d_in, const int* in_sizes, int n_in,
                              void* d_out, int out_size, void* d_ws, size_t ws_size,
                              hipStream_t stream) {
    const float* in_feas  = (const float*)d_in[0];
    const float* codebook = (const float*)d_in[2];
    const float* att_w    = (const float*)d_in[3];
    const float* att_b    = (const float*)d_in[4];
    const float* ex_w     = (const float*)d_in[5];
    const float* ex_b     = (const float*)d_in[6];
    const float* qkv_w    = (const float*)d_in[7];
    const float* qkv_b    = (const float*)d_in[8];
    const float* proj_w   = (const float*)d_in[9];
    const float* proj_b   = (const float*)d_in[10];

    float* out    = (float*)d_out;
    float* outVd  = out;
    float* outEnc = out + 393216;
    float* outRm  = out + 393216 + 12544;

    float* ws = (float*)d_ws;
    // CORRECTED sizes: CBhi = 8192*768 bf16 = 3,145,728 fl; Ahi/Vhi = 12544*768 bf16
    // = 4,816,896 fl each. Vhi overlays cand+CBhi+Ahi-head (dead by vqf_split time).
    float*    cn    = ws + 0;                          // 8,192
    float4*   cand  = (float4*)(ws + 8192);            // 1,605,632 fl (12544*32 f4)
    ushort_t* CBhi  = (ushort_t*)(ws + 1613824);       // 3,145,728 fl -> 4,759,552
    ushort_t* Ahi   = (ushort_t*)(ws + 4759552);       // 4,816,896 fl -> 9,576,448
    ushort_t* attHi = (ushort_t*)(ws + 9576448);       // 30,720 fl   -> 9,607,168
    ushort_t* exHi  = (ushort_t*)(ws + 9607168);       // 6,144 fl    -> 9,613,312
    int*      idx   = (int*)(ws + 9613312);            // 12,544      -> 9,625,856
    float*    XW    = ws + 9625856;                    // 200,704     -> 9,826,560
    float*    sm    = ws + 9826560;                    // 12,544      -> 9,839,104
    float*    OUTC  = ws + 9839104;                    // 1,003,520   -> 10,842,624
    float*    seq   = ws + 10842624;                   // 393,216     -> 11,235,840
    float*    qkvb  = ws + 11235840;                   // 1,179,648   -> 12,415,488
    float*    attnb = ws + 12415488;                   // 393,216     -> 12,808,704 (51.2 MB)
    // overlay: Vhi over [cand, CBhi, Ahi-head] — all dead before vqf_split
    ushort_t* Vhi   = (ushort_t*)(ws + 8192);          // 4,816,896 fl -> 4,825,088

    hipLaunchKernelGGL(cnorm_kernel, dim3(K_), dim3(64), 0, stream, codebook, cn);
    hipLaunchKernelGGL(cb_split_kernel, dim3(3072), dim3(256), 0, stream, codebook, CBhi);
    hipLaunchKernelGGL(a_split_kernel, dim3(784), dim3(256), 0, stream, in_feas, Ahi);
    hipLaunchKernelGGL(wsplit_kernel, dim3(36), dim3(256), 0, stream, att_w, ex_w, attHi, exHi);
    hipLaunchKernelGGL(vq_mfma_kernel, dim3(8, 196), dim3(256), 0, stream,
                       Ahi, CBhi, cn, cand);
    hipLaunchKernelGGL((convgemm_kernel<1>), dim3(98), dim3(256), 0, stream,
                       Ahi, exHi, XW);
    hipLaunchKernelGGL(rescore_kernel, dim3(M_ / 4), dim3(256), 0, stream,
                       cand, in_feas, codebook, idx, outEnc);
    hipLaunchKernelGGL(mm_finish_kernel, dim3(B_), dim3(256), 0, stream, XW, ex_b, sm);
    hipLaunchKernelGGL(vqf_split_kernel, dim3(784), dim3(256), 0, stream,
                       in_feas, codebook, idx, sm, Vhi);
    hipLaunchKernelGGL((convgemm_kernel<5>), dim3(98), dim3(256), 0, stream,
                       Vhi, attHi, OUTC);
    hipLaunchKernelGGL(rm_finish_kernel, dim3(392), dim3(256), 0, stream,
                       OUTC, att_b, outRm);
    hipLaunchKernelGGL(regions_kernel, dim3(B_, 3), dim3(256), 0, stream,
                       Vhi, outRm, seq);
    hipLaunchKernelGGL(gemm_bias_kernel, dim3(8, 36), dim3(256), 0, stream,
                       seq, qkv_w, qkv_b, qkvb, 512, 2304, 768);
    hipLaunchKernelGGL(attn_kernel, dim3(BP_, NH_), dim3(256), 0, stream, qkvb, attnb);
    hipLaunchKernelGGL(gemm_bias_kernel, dim3(8, 12), dim3(256), 0, stream,
                       attnb, proj_w, proj_b, outVd, 512, 768, 768);
}

// Round 7
// 344.954 us; speedup vs baseline: 11.3281x; 1.5894x over previous
//
#include <hip/hip_runtime.h>
#include <math.h>

#define B_   64
#define L_   196
#define C_   768
#define K_   8192
#define R_   8
#define HW_  14
#define M_   (B_*L_)     // 12544
#define NH_  8
#define DH_  96
#define BP_  16
#define NT_  32

typedef unsigned short ushort_t;
typedef __attribute__((ext_vector_type(8))) short short8v;   // 8 bf16 (4 VGPR)
typedef __attribute__((ext_vector_type(4))) float f32x4;     // MFMA 16x16 f32 acc
typedef __attribute__((ext_vector_type(4))) int   i32x4;     // MFMA i8 operands/acc

// ---------------- utilities ----------------
__device__ inline float wave_reduce_sum(float v) {
    #pragma unroll
    for (int o = 32; o >= 1; o >>= 1) v += __shfl_xor(v, o, 64);
    return v;
}
__device__ inline float wave_reduce_max(float v) {
    #pragma unroll
    for (int o = 32; o >= 1; o >>= 1) v = fmaxf(v, __shfl_xor(v, o, 64));
    return v;
}

__device__ inline ushort_t f2bf_rne(float f) {
    unsigned u = __float_as_uint(f);
    unsigned r = u + 0x7fffu + ((u >> 16) & 1u);
    return (ushort_t)(r >> 16);
}
__device__ inline float bf2f(ushort_t h) { return __uint_as_float(((unsigned)h) << 16); }

__device__ inline char q8(float f, float s) {
    int q = __float2int_rn(f * s);
    return (char)(q < -127 ? -127 : (q > 127 ? 127 : q));
}

__device__ inline void gload_lds16(const void* gsrc, void* ldst) {
    __builtin_amdgcn_global_load_lds(
        (const __attribute__((address_space(1))) unsigned int*)gsrc,
        (__attribute__((address_space(3))) unsigned int*)ldst, 16, 0, 0);
}

// merge two sorted pairs -> sorted top-2 of union (lowest-index tie-break)
__device__ inline void top2_merge(float& v1, int& i1, float& v2, int& i2,
                                  float w1, int j1, float w2, int j2) {
    bool fw = (v1 < w1) || (v1 == w1 && i1 <= j1);
    float a1 = fw ? v1 : w1;  int ai1 = fw ? i1 : j1;
    float lb = fw ? w1 : v1;  int lbi = fw ? j1 : i1;
    float wsv = fw ? v2 : w2; int wsi = fw ? i2 : j2;
    bool sb = (lb < wsv) || (lb == wsv && lbi < wsi);
    v1 = a1; i1 = ai1;
    v2 = sb ? lb : wsv; i2 = sb ? lbi : wsi;
}

__device__ inline void ce4(float& v0, int& j0, float& v1, int& j1) {
    bool sw = (v1 < v0) || (v1 == v0 && j1 < j0);
    float tv = sw ? v1 : v0, uv = sw ? v0 : v1;
    int tj = sw ? j1 : j0, uj = sw ? j0 : j1;
    v0 = tv; j0 = tj; v1 = uv; j1 = uj;
}
__device__ inline void pickmin(float& v, int& j, float bv, int bj) {
    if (bv < v || (bv == v && bj < j)) { v = bv; j = bj; }
}

// ---------------- codebook -> int8 frags + norms (fused) ----------------
// CBq layout: [cb_g(512)][kb(12)][l(64)][e(16)] bytes; code=cb_g*16+(l&15), k=kb*64+(l>>4)*16+e
__global__ __launch_bounds__(256) void cbq_kernel(const float* __restrict__ CB,
                                                  char* __restrict__ CBq,
                                                  float* __restrict__ cnq) {
    __shared__ float xs[16 * 776];
    const int t = threadIdx.x;
    const int blk = blockIdx.x;
    const float4* src = (const float4*)(CB + (size_t)blk * 16 * C_);
    #pragma unroll
    for (int i = 0; i < 12; ++i) {
        int idx4 = t + i * 256;
        int r = idx4 / 192, c4 = idx4 - r * 192;
        ((float4*)(xs + r * 776))[c4] = src[idx4];
    }
    __syncthreads();
    #pragma unroll
    for (int i = 0; i < 3; ++i) {
        int s = t + i * 256;
        int kb = s >> 6, l = s & 63;
        int row = l & 15;
        int k0 = kb * 64 + ((l >> 4) << 4);
        union { char c[16]; i32x4 v; } Q;
        #pragma unroll
        for (int e = 0; e < 16; ++e) Q.c[e] = q8(xs[row * 776 + k0 + e], 32.f);
        *(i32x4*)&CBq[(((size_t)blk * 12 + kb) << 10) + l * 16] = Q.v;
    }
    // norms: thread t -> row t&15, chunk t>>4 (48 elems)
    int row = t & 15, chunk = t >> 4;
    float sum = 0.f;
    #pragma unroll
    for (int j = 0; j < 48; ++j) { float v = xs[row * 776 + chunk * 48 + j]; sum += v * v; }
    sum += __shfl_xor(sum, 16, 64);
    sum += __shfl_xor(sum, 32, 64);
    __shared__ float red[4][16];
    if ((t & 63) < 16) red[t >> 6][t & 15] = sum;
    __syncthreads();
    if (t < 16) cnq[blk * 16 + t] = (red[0][t] + red[1][t] + red[2][t] + red[3][t]) * 1024.f;
}

// ---------------- A -> int8 frags ----------------
__global__ __launch_bounds__(256) void aq_kernel(const float* __restrict__ X,
                                                 char* __restrict__ Aq) {
    __shared__ float xs[16 * 776];
    const int t = threadIdx.x;
    const int rg = blockIdx.x;
    const float4* src = (const float4*)(X + (size_t)rg * 16 * C_);
    #pragma unroll
    for (int i = 0; i < 12; ++i) {
        int idx4 = t + i * 256;
        int r = idx4 / 192, c4 = idx4 - r * 192;
        ((float4*)(xs + r * 776))[c4] = src[idx4];
    }
    __syncthreads();
    #pragma unroll
    for (int i = 0; i < 3; ++i) {
        int s = t + i * 256;
        int kb = s >> 6, l = s & 63;
        int row = l & 15;
        int k0 = kb * 64 + ((l >> 4) << 4);
        union { char c[16]; i32x4 v; } Q;
        #pragma unroll
        for (int e = 0; e < 16; ++e) Q.c[e] = q8(xs[row * 776 + k0 + e], 32.f);
        *(i32x4*)&Aq[(((size_t)rg * 12 + kb) << 10) + l * 16] = Q.v;
    }
}

// ---------------- conv weights: att bf16 frags + ex int8 frags ----------------
__global__ __launch_bounds__(256) void wsplit_kernel(const float* __restrict__ att_w,
                                                     const float* __restrict__ ex_w,
                                                     ushort_t* __restrict__ attHi,
                                                     char* __restrict__ exq) {
    int gid = blockIdx.x * 256 + threadIdx.x;
    if (gid < 7680) {                                  // att bf16: 5 cb x 24 kb x 64 l
        int cb = gid / 1536;
        int rem = gid - cb * 1536;
        int l = rem & 63;
        int col = cb * 16 + (l & 15);
        int k = ((rem >> 6) << 5) + ((l >> 4) << 3);
        union { ushort_t u[8]; short8v v; } H;
        #pragma unroll
        for (int e = 0; e < 8; ++e) {
            int c = k + e;
            float f = (col < 72) ? att_w[(size_t)(col & 7) * 6912 + c * 9 + (col >> 3)] : 0.f;
            H.u[e] = f2bf_rne(f);
        }
        *(short8v*)&attHi[(size_t)gid * 8] = H.v;
    } else if (gid < 8448) {                           // ex int8: 12 kb x 64 l
        int g2 = gid - 7680;
        int l = g2 & 63;
        int col = l & 15;
        int k0 = ((g2 >> 6) << 6) + ((l >> 4) << 4);
        union { char c[16]; i32x4 v; } Q;
        #pragma unroll
        for (int e = 0; e < 16; ++e) {
            int k = k0 + e;
            float f = (col < 9) ? ex_w[k * 9 + col] : 0.f;
            Q.c[e] = q8(f, 1024.f);
        }
        *(i32x4*)&exq[(size_t)g2 * 16] = Q.v;
    }
}

// ---------------- qkv/proj weights -> bf16 frags ----------------
__global__ __launch_bounds__(256) void wgemm_split_kernel(const float* __restrict__ qkv_w,
                                                          const float* __restrict__ proj_w,
                                                          ushort_t* __restrict__ wqkvF,
                                                          ushort_t* __restrict__ wprojF) {
    int gid = blockIdx.x * 256 + threadIdx.x;
    const float* W; ushort_t* D; int g2;
    if (gid < 221184) { W = qkv_w; D = wqkvF; g2 = gid; }
    else { W = proj_w; D = wprojF; g2 = gid - 221184; }
    int cb = g2 / 1536;
    int rem = g2 - cb * 1536;
    int l = rem & 63;
    int col = cb * 16 + (l & 15);
    int k = ((rem >> 6) << 5) + ((l >> 4) << 3);
    union { ushort_t u[8]; short8v v; } H;
    #pragma unroll
    for (int e = 0; e < 8; ++e) H.u[e] = f2bf_rne(W[(size_t)col * 768 + k + e]);
    *(short8v*)&D[(size_t)g2 * 8] = H.v;
}

// ---------------- VQ: int8 MFMA, BM=64 BN=512 BK=64, dbuf + counted vmcnt ----
// grid (8, 196): g = code split (1024 codes, XCD-pinned), mt = 64-row tile
__global__ __launch_bounds__(256, 2) void vq_i8_kernel(const char* __restrict__ Aq,
                                                       const char* __restrict__ CBq,
                                                       const float* __restrict__ cnq,
                                                       float4* __restrict__ cand) {
    __shared__ __align__(16) char AqL[2][4096];
    __shared__ __align__(16) char BqL[2][32768];
    const int tid = threadIdx.x;
    const int l = tid & 63, w = tid >> 6;              // w = col quadrant 0..3
    const int g = blockIdx.x;
    const int mt = blockIdx.y;
    const int row0 = mt * 64;
    const int rg0 = mt * 4;

    float v1[4][4], v2[4][4]; int i1[4][4], i2[4][4];
    #pragma unroll
    for (int mf = 0; mf < 4; ++mf)
        #pragma unroll
        for (int rg = 0; rg < 4; ++rg) {
            v1[mf][rg] = INFINITY; v2[mf][rg] = INFINITY;
            i1[mf][rg] = 0x7fffffff; i2[mf][rg] = 0x7fffffff;
        }

    auto STAGE = [&](int buf, int u) {
        int ch = (u >= 12) ? 1 : 0;
        int st = u - ch * 12;
        int cbase = g * 64 + ch * 32;
        #pragma unroll
        for (int i = 0; i < 9; ++i) {
            int s = w * 9 + i;
            if (s < 4)
                gload_lds16(&Aq[(((size_t)(rg0 + s) * 12 + st) << 10) + l * 16],
                            &AqL[buf][s << 10]);
            else {
                int cb = s - 4;
                gload_lds16(&CBq[(((size_t)(cbase + cb) * 12 + st) << 10) + l * 16],
                            &BqL[buf][cb << 10]);
            }
        }
    };

    int cur = 0;
    STAGE(0, 0);
    __syncthreads();                                   // full drain once (prologue)

    #pragma unroll 1
    for (int ch = 0; ch < 2; ++ch) {
        i32x4 acc[4][8];
        #pragma unroll
        for (int mf = 0; mf < 4; ++mf)
            #pragma unroll
            for (int nf = 0; nf < 8; ++nf) acc[mf][nf] = (i32x4){0, 0, 0, 0};

        #pragma unroll 1
        for (int st = 0; st < 12; ++st) {
            int u = ch * 12 + st;
            if (u < 23) STAGE(cur ^ 1, u + 1);         // prefetch next stage
            i32x4 aq[4];
            #pragma unroll
            for (int mf = 0; mf < 4; ++mf)
                aq[mf] = *(const i32x4*)&AqL[cur][(mf << 10) + l * 16];
            #pragma unroll
            for (int nf = 0; nf < 8; ++nf) {
                i32x4 bq = *(const i32x4*)&BqL[cur][((w * 8 + nf) << 10) + l * 16];
                #pragma unroll
                for (int mf = 0; mf < 4; ++mf)
                    acc[mf][nf] = __builtin_amdgcn_mfma_i32_16x16x64_i8(aq[mf], bq, acc[mf][nf], 0, 0, 0);
            }
            // counted drain: wait only for the PREVIOUS buffer's loads (keep 9 in flight)
            asm volatile("s_waitcnt vmcnt(9)" ::: "memory");
            __builtin_amdgcn_sched_barrier(0);
            __builtin_amdgcn_s_barrier();
            __builtin_amdgcn_sched_barrier(0);
            cur ^= 1;
        }
        // chunk epilogue: d~ = 1024*(cn - 2 x.c); per-lane top-2 insert
        #pragma unroll
        for (int nf = 0; nf < 8; ++nf) {
            int code = g * 1024 + ch * 512 + w * 128 + nf * 16 + (l & 15);
            float cnv = cnq[code];
            #pragma unroll
            for (int mf = 0; mf < 4; ++mf)
                #pragma unroll
                for (int rg = 0; rg < 4; ++rg) {
                    float d = fmaf(-2.f, (float)acc[mf][nf][rg], cnv);
                    bool c1 = d < v1[mf][rg];
                    bool c2 = d < v2[mf][rg];
                    float nv2 = c1 ? v1[mf][rg] : (c2 ? d : v2[mf][rg]);
                    int   ni2 = c1 ? i1[mf][rg] : (c2 ? code : i2[mf][rg]);
                    v2[mf][rg] = nv2; i2[mf][rg] = ni2;
                    if (c1) { v1[mf][rg] = d; i1[mf][rg] = code; }
                }
        }
    }
    // cross-lane exact top-2 per row over the 16 col-lanes; write subset pair
    #pragma unroll
    for (int mf = 0; mf < 4; ++mf)
        #pragma unroll
        for (int rg = 0; rg < 4; ++rg) {
            float a1 = v1[mf][rg], a2 = v2[mf][rg];
            int b1 = i1[mf][rg], b2 = i2[mf][rg];
            #pragma unroll
            for (int off = 8; off >= 1; off >>= 1) {
                float w1 = __shfl_xor(a1, off, 64), w2 = __shfl_xor(a2, off, 64);
                int j1 = __shfl_xor(b1, off, 64), j2 = __shfl_xor(b2, off, 64);
                top2_merge(a1, b1, a2, b2, w1, j1, w2, j2);
            }
            if ((l & 15) == 0) {
                int row = row0 + mf * 16 + (l >> 4) * 4 + rg;
                cand[(size_t)row * 32 + g * 4 + w] =
                    make_float4(a1, __int_as_float(b1), a2, __int_as_float(b2));
            }
        }
}

// ---------------- rescore: exact top-4 of 32 subset-pairs, fp64 re-eval ------
__global__ __launch_bounds__(256) void rescore_kernel(const float4* __restrict__ cand,
                                                      const float* __restrict__ X,
                                                      const float* __restrict__ CB,
                                                      int* __restrict__ idx,
                                                      float* __restrict__ encOut) {
    int w = threadIdx.x >> 6, l = threadIdx.x & 63;
    int r = blockIdx.x * 4 + w;
    float a0, a1, a2, a3; int j0, j1, j2, j3;
    if (l < 32) {
        float4 c = cand[(size_t)r * 32 + l];
        a0 = c.x; j0 = __float_as_int(c.y);
        a1 = c.z; j1 = __float_as_int(c.w);
    } else { a0 = INFINITY; a1 = INFINITY; j0 = 0x7fffffff; j1 = 0x7fffffff; }
    a2 = INFINITY; a3 = INFINITY; j2 = 0x7fffffff; j3 = 0x7fffffff;
    #pragma unroll
    for (int off = 32; off >= 1; off >>= 1) {
        float b0 = __shfl_xor(a0, off, 64), b1 = __shfl_xor(a1, off, 64);
        float b2 = __shfl_xor(a2, off, 64), b3 = __shfl_xor(a3, off, 64);
        int p0 = __shfl_xor(j0, off, 64), p1 = __shfl_xor(j1, off, 64);
        int p2 = __shfl_xor(j2, off, 64), p3 = __shfl_xor(j3, off, 64);
        pickmin(a0, j0, b3, p3); pickmin(a1, j1, b2, p2);
        pickmin(a2, j2, b1, p1); pickmin(a3, j3, b0, p0);
        ce4(a0, j0, a2, j2); ce4(a1, j1, a3, j3);
        ce4(a0, j0, a1, j1); ce4(a2, j2, a3, j3);
    }
    double dot0 = 0, dot1 = 0, dot2 = 0, dot3 = 0;
    double nn0 = 0, nn1 = 0, nn2 = 0, nn3 = 0;
    const float* xr = X + (size_t)r * C_;
    #pragma unroll
    for (int jj = 0; jj < 12; ++jj) {
        int c = l * 12 + jj;
        double x = (double)xr[c];
        double c0 = (double)CB[(size_t)j0 * C_ + c]; dot0 += x * c0; nn0 += c0 * c0;
        double c1 = (double)CB[(size_t)j1 * C_ + c]; dot1 += x * c1; nn1 += c1 * c1;
        double c2 = (double)CB[(size_t)j2 * C_ + c]; dot2 += x * c2; nn2 += c2 * c2;
        double c3 = (double)CB[(size_t)j3 * C_ + c]; dot3 += x * c3; nn3 += c3 * c3;
    }
    #pragma unroll
    for (int off = 32; off >= 1; off >>= 1) {
        dot0 += __shfl_xor(dot0, off, 64); dot1 += __shfl_xor(dot1, off, 64);
        dot2 += __shfl_xor(dot2, off, 64); dot3 += __shfl_xor(dot3, off, 64);
        nn0 += __shfl_xor(nn0, off, 64); nn1 += __shfl_xor(nn1, off, 64);
        nn2 += __shfl_xor(nn2, off, 64); nn3 += __shfl_xor(nn3, off, 64);
    }
    if (l == 0) {
        double d0 = nn0 - 2.0 * dot0, d1 = nn1 - 2.0 * dot1;
        double d2 = nn2 - 2.0 * dot2, d3 = nn3 - 2.0 * dot3;
        double best = d0; int bi = j0;
        if (d1 < best || (d1 == best && j1 < bi)) { best = d1; bi = j1; }
        if (d2 < best || (d2 == best && j2 < bi)) { best = d2; bi = j2; }
        if (d3 < best || (d3 == best && j3 < bi)) { best = d3; bi = j3; }
        idx[r] = bi;
        encOut[r] = (float)bi;
    }
}

// ---------------- motion conv GEMM (int8): XW[12544][16] ----------------
__global__ __launch_bounds__(256) void convgemm_i8_kernel(const char* __restrict__ Aq,
                                                          const char* __restrict__ Bq,
                                                          float* __restrict__ out) {
    __shared__ __align__(16) char AqL[8 * 1024];
    __shared__ __align__(16) char BqL[1024];
    const int tid = threadIdx.x;
    const int l = tid & 63, w = tid >> 6;
    const int rg0 = blockIdx.x * 8, row0 = blockIdx.x * 128;
    i32x4 acc[2];
    acc[0] = (i32x4){0, 0, 0, 0}; acc[1] = (i32x4){0, 0, 0, 0};
    #pragma unroll 1
    for (int st = 0; st < 12; ++st) {
        __syncthreads();
        #pragma unroll
        for (int i = 0; i < 3; ++i) {
            int s = w * 3 + i;
            if (s < 8)
                gload_lds16(&Aq[(((size_t)(rg0 + s) * 12 + st) << 10) + l * 16], &AqL[s << 10]);
            else if (s == 8)
                gload_lds16(&Bq[((size_t)st << 10) + l * 16], &BqL[0]);
        }
        __syncthreads();
        i32x4 bq = *(const i32x4*)&BqL[l * 16];
        #pragma unroll
        for (int mf = 0; mf < 2; ++mf) {
            i32x4 aq = *(const i32x4*)&AqL[((w * 2 + mf) << 10) + l * 16];
            acc[mf] = __builtin_amdgcn_mfma_i32_16x16x64_i8(aq, bq, acc[mf], 0, 0, 0);
        }
    }
    #pragma unroll
    for (int mf = 0; mf < 2; ++mf)
        #pragma unroll
        for (int rg = 0; rg < 4; ++rg) {
            int row = row0 + w * 32 + mf * 16 + (l >> 4) * 4 + rg;
            out[(size_t)row * 16 + (l & 15)] = (float)acc[mf][rg] * (1.f / 32768.f);
        }
}

// ---------------- bf16 conv GEMM (region mask): out[12544][NF*16] -----------
template<int NF>
__global__ __launch_bounds__(256) void convgemm_kernel(const ushort_t* __restrict__ Ahi_g,
                                                       const ushort_t* __restrict__ Bhi_g,
                                                       float* __restrict__ out) {
    __shared__ __align__(16) ushort_t AhL[16 * 512];
    __shared__ __align__(16) ushort_t BhL[NF * 2 * 512];
    const int TOT = 16 + 2 * NF;
    const int PW = (TOT + 3) >> 2;
    const int tid = threadIdx.x;
    const int l = tid & 63, w = tid >> 6;
    const int rg0 = blockIdx.x * 8;
    const int row0 = blockIdx.x * 128;
    f32x4 acc[2][NF];
    #pragma unroll
    for (int mf = 0; mf < 2; ++mf)
        #pragma unroll
        for (int nf = 0; nf < NF; ++nf) acc[mf][nf] = (f32x4){0.f, 0.f, 0.f, 0.f};
    #pragma unroll 1
    for (int st = 0; st < 12; ++st) {
        __syncthreads();
        #pragma unroll
        for (int i = 0; i < PW; ++i) {
            int s = w * PW + i;
            if (s < 16) {
                int rb = s >> 1, kb = s & 1;
                gload_lds16(&Ahi_g[(((size_t)(rg0 + rb) * 24 + st * 2 + kb) << 9) + l * 8], &AhL[s << 9]);
            } else if (s < TOT) {
                int t2 = s - 16;
                int cb = t2 >> 1, kb = t2 & 1;
                gload_lds16(&Bhi_g[(((size_t)cb * 24 + st * 2 + kb) << 9) + l * 8], &BhL[t2 << 9]);
            }
        }
        __syncthreads();
        #pragma unroll
        for (int kf = 0; kf < 2; ++kf) {
            short8v ah[2];
            #pragma unroll
            for (int mf = 0; mf < 2; ++mf)
                ah[mf] = *(const short8v*)&AhL[(((w * 2 + mf) * 2 + kf) << 9) + l * 8];
            #pragma unroll
            for (int nf = 0; nf < NF; ++nf) {
                short8v bh = *(const short8v*)&BhL[((nf * 2 + kf) << 9) + l * 8];
                #pragma unroll
                for (int mf = 0; mf < 2; ++mf)
                    acc[mf][nf] = __builtin_amdgcn_mfma_f32_16x16x32_bf16(ah[mf], bh, acc[mf][nf], 0, 0, 0);
            }
        }
    }
    #pragma unroll
    for (int mf = 0; mf < 2; ++mf)
        #pragma unroll
        for (int nf = 0; nf < NF; ++nf)
            #pragma unroll
            for (int rg = 0; rg < 4; ++rg) {
                int row = row0 + w * 32 + mf * 16 + (l >> 4) * 4 + rg;
                out[(size_t)row * (NF * 16) + nf * 16 + (l & 15)] = acc[mf][nf][rg];
            }
}

// ---------------- generic frag-GEMM with bias: out[M][N] fp32 ----------------
template<int NF>
__global__ __launch_bounds__(256) void gemm_frag_kernel(const ushort_t* __restrict__ Af,
                                                        const ushort_t* __restrict__ Bf,
                                                        const float* __restrict__ bias,
                                                        float* __restrict__ out, int N) {
    __shared__ __align__(16) ushort_t AhL[16 * 512];
    __shared__ __align__(16) ushort_t BhL[2 * NF * 512];
    const int TOT = 16 + 2 * NF;
    const int PW = (TOT + 3) >> 2;
    const int tid = threadIdx.x;
    const int l = tid & 63, w = tid >> 6;
    const int rg0 = blockIdx.x * 8, row0 = blockIdx.x * 128;
    const int cb0 = blockIdx.y * NF;
    f32x4 acc[2][NF];
    #pragma unroll
    for (int mf = 0; mf < 2; ++mf)
        #pragma unroll
        for (int nf = 0; nf < NF; ++nf) acc[mf][nf] = (f32x4){0.f, 0.f, 0.f, 0.f};
    #pragma unroll 1
    for (int st = 0; st < 12; ++st) {
        __syncthreads();
        #pragma unroll
        for (int i = 0; i < PW; ++i) {
            int s = w * PW + i;
            if (s < 16) {
                int rb = s >> 1, kb = s & 1;
                gload_lds16(&Af[(((size_t)(rg0 + rb) * 24 + st * 2 + kb) << 9) + l * 8], &AhL[s << 9]);
            } else if (s < TOT) {
                int t2 = s - 16;
                int cb = t2 >> 1, kb = t2 & 1;
                gload_lds16(&Bf[(((size_t)(cb0 + cb) * 24 + st * 2 + kb) << 9) + l * 8], &BhL[t2 << 9]);
            }
        }
        __syncthreads();
        #pragma unroll
        for (int kf = 0; kf < 2; ++kf) {
            short8v ah[2];
            #pragma unroll
            for (int mf = 0; mf < 2; ++mf)
                ah[mf] = *(const short8v*)&AhL[(((w * 2 + mf) * 2 + kf) << 9) + l * 8];
            #pragma unroll
            for (int nf = 0; nf < NF; ++nf) {
                short8v bh = *(const short8v*)&BhL[((nf * 2 + kf) << 9) + l * 8];
                #pragma unroll
                for (int mf = 0; mf < 2; ++mf)
                    acc[mf][nf] = __builtin_amdgcn_mfma_f32_16x16x32_bf16(ah[mf], bh, acc[mf][nf], 0, 0, 0);
            }
        }
    }
    #pragma unroll
    for (int mf = 0; mf < 2; ++mf)
        #pragma unroll
        for (int nf = 0; nf < NF; ++nf) {
            int col = (cb0 + nf) * 16 + (l & 15);
            float bv = bias[col];
            #pragma unroll
            for (int rg = 0; rg < 4; ++rg) {
                int row = row0 + w * 32 + mf * 16 + (l >> 4) * 4 + rg;
                out[(size_t)row * N + col] = acc[mf][nf][rg] + bv;
            }
        }
}

// ---------------- mm finish: shifted-add + frame diff + softmax --------------
__global__ __launch_bounds__(256) void mm_finish_kernel(const float* __restrict__ XW,
                                                        const float* __restrict__ ex_b,
                                                        float* __restrict__ sm) {
    int b = blockIdx.x, t = threadIdx.x;
    float val = -INFINITY;
    if (t < L_) {
        if ((b & 3) == 0) val = ex_b[0];
        else {
            int yy = t / HW_, xx = t - (t / HW_) * HW_;
            float acc = 0.f;
            #pragma unroll
            for (int dy = 0; dy < 3; ++dy) {
                int sy = yy + dy - 1; if (sy < 0 || sy >= HW_) continue;
                #pragma unroll
                for (int dx = 0; dx < 3; ++dx) {
                    int sx = xx + dx - 1; if (sx < 0 || sx >= HW_) continue;
                    int q = sy * HW_ + sx, tap = dy * 3 + dx;
                    acc += XW[((size_t)b * L_ + q) * 16 + tap]
                         - XW[((size_t)(b - 1) * L_ + q) * 16 + tap];
                }
            }
            val = acc + ex_b[0];
        }
    }
    __shared__ float red[4];
    float mw = wave_reduce_max(val);
    if ((t & 63) == 0) red[t >> 6] = mw;
    __syncthreads();
    float mx = fmaxf(fmaxf(red[0], red[1]), fmaxf(red[2], red[3]));
    float e = (t < L_) ? expf(val - mx) : 0.f;
    __syncthreads();
    float sw = wave_reduce_sum(e);
    if ((t & 63) == 0) red[t >> 6] = sw;
    __syncthreads();
    float s = red[0] + red[1] + red[2] + red[3];
    if (t < L_) sm[b * L_ + t] = e / s;
}

// ---------------- vqf -> fragment-linear bf16 ----------------
__global__ __launch_bounds__(256) void vqf_split_kernel(const float* __restrict__ X,
                                                        const float* __restrict__ CB,
                                                        const int* __restrict__ idx,
                                                        const float* __restrict__ sm,
                                                        ushort_t* __restrict__ Vhi) {
    const int rg = blockIdx.x, t = threadIdx.x;
    #pragma unroll
    for (int i = 0; i < 6; ++i) {
        int s = t + i * 256;
        int kb = s >> 6, l = s & 63;
        int row = rg * 16 + (l & 15);
        int k = kb * 32 + ((l >> 4) << 3);
        int kidx = idx[row];
        float sc = sm[row];
        const float* xp = &X[(size_t)row * C_ + k];
        const float* cp = &CB[(size_t)kidx * C_ + k];
        union { ushort_t u[8]; short8v v; } H;
        #pragma unroll
        for (int e = 0; e < 8; ++e) H.u[e] = f2bf_rne(cp[e] + xp[e] * sc);
        *(short8v*)&Vhi[((size_t)rg * 1536 + s) * 8] = H.v;
    }
}

// ---------------- rm finish: shifted-add of OUTC + bias ----------------
__global__ __launch_bounds__(256) void rm_finish_kernel(const float* __restrict__ OUTC,
                                                        const float* __restrict__ att_b,
                                                        float* __restrict__ rmOut) {
    int gid = blockIdx.x * 256 + threadIdx.x;
    if (gid >= B_ * R_ * L_) return;
    int b = gid / (R_ * L_);
    int rem = gid - b * (R_ * L_);
    int r = rem / L_, p = rem - r * L_;
    int yy = p / HW_, xx = p - yy * HW_;
    float acc = att_b[r];
    #pragma unroll
    for (int dy = 0; dy < 3; ++dy) {
        int sy = yy + dy - 1; if (sy < 0 || sy >= HW_) continue;
        #pragma unroll
        for (int dx = 0; dx < 3; ++dx) {
            int sx = xx + dx - 1; if (sx < 0 || sx >= HW_) continue;
            int q = sy * HW_ + sx, tap = dy * 3 + dx;
            acc += OUTC[((size_t)b * L_ + q) * 80 + tap * 8 + r];
        }
    }
    rmOut[gid] = acc;
}

// ---------------- regions einsum from Vhi -> seq frags (bf16) ----------------
__global__ __launch_bounds__(256) void regions_kernel(const ushort_t* __restrict__ Vhi,
                                                      const float* __restrict__ rm,
                                                      ushort_t* __restrict__ seqF) {
    int b = blockIdx.x, cg = blockIdx.y, t = threadIdx.x;
    __shared__ float rms[R_ * L_];
    for (int i = t; i < R_ * L_; i += 256) rms[i] = rm[(size_t)b * R_ * L_ + i];
    __syncthreads();
    const float inv = 1.f / 196.f;
    int c = cg * 256 + t;
    int kb = c >> 5, q = (c >> 3) & 3, e = c & 7;
    float acc[R_] = {};
    for (int p = 0; p < L_; ++p) {
        int row = b * L_ + p;
        int rg = row >> 4, rr = row & 15;
        size_t a = (((size_t)rg * 24 + kb) * 64 + q * 16 + rr) * 8 + e;
        float x = bf2f(Vhi[a]);
        #pragma unroll
        for (int r = 0; r < R_; ++r) acc[r] += x * rms[r * L_ + p];
    }
    #pragma unroll
    for (int r = 0; r < R_; ++r) {
        int row = b * 8 + r;
        int rg2 = row >> 4, rr = row & 15;
        seqF[(((size_t)rg2 * 24 + kb) * 64 + q * 16 + rr) * 8 + e] = f2bf_rne(acc[r] * inv);
    }
}

// ---------------- per-(batch,head) attention -> frag-linear bf16 out ---------
__global__ __launch_bounds__(256) void attn_kernel(const float* __restrict__ qkv,
                                                   ushort_t* __restrict__ outF) {
    int bp = blockIdx.x, h = blockIdx.y;
    __shared__ float qs[NT_][DH_], ks[NT_][DH_], vs[NT_][DH_];
    __shared__ float sc[NT_][NT_ + 1];
    int tid = threadIdx.x;
    for (int e = tid; e < NT_ * DH_; e += 256) {
        int n = e / DH_, d = e - n * DH_;
        size_t base = ((size_t)(bp * NT_ + n)) * 2304 + h * DH_ + d;
        qs[n][d] = qkv[base];
        ks[n][d] = qkv[base + 768];
        vs[n][d] = qkv[base + 1536];
    }
    __syncthreads();
    const float scale = 1.0f / sqrtf((float)DH_);
    for (int e = tid; e < NT_ * NT_; e += 256) {
        int n = e >> 5, m = e & 31;
        float s = 0.f;
        #pragma unroll 8
        for (int d = 0; d < DH_; ++d) s += qs[n][d] * ks[m][d];
        sc[n][m] = s * scale;
    }
    __syncthreads();
    if (tid < NT_) {
        float mx = -INFINITY;
        #pragma unroll
        for (int m = 0; m < NT_; ++m) mx = fmaxf(mx, sc[tid][m]);
        float sum = 0.f;
        #pragma unroll
        for (int m = 0; m < NT_; ++m) { float e2 = expf(sc[tid][m] - mx); sc[tid][m] = e2; sum += e2; }
        float inv = 1.f / sum;
        #pragma unroll
        for (int m = 0; m < NT_; ++m) sc[tid][m] *= inv;
    }
    __syncthreads();
    for (int e = tid; e < NT_ * DH_; e += 256) {
        int n = e / DH_, d = e - n * DH_;
        float o = 0.f;
        #pragma unroll
        for (int m = 0; m < NT_; ++m) o += sc[n][m] * vs[m][d];
        int row = bp * NT_ + n, c = h * DH_ + d;
        outF[(((size_t)(row >> 4) * 24 + (c >> 5)) * 64 + ((c >> 3) & 3) * 16 + (row & 15)) * 8 + (c & 7)]
            = f2bf_rne(o);
    }
}

// ---------------- launch ----------------
extern "C" void kernel_launch(void* const* d_in, const int* in_sizes, int n_in,
                              void* d_out, int out_size, void* d_ws, size_t ws_size,
                              hipStream_t stream) {
    const float* in_feas  = (const float*)d_in[0];
    const float* codebook = (const float*)d_in[2];
    const float* att_w    = (const float*)d_in[3];
    const float* att_b    = (const float*)d_in[4];
    const float* ex_w     = (const float*)d_in[5];
    const float* ex_b     = (const float*)d_in[6];
    const float* qkv_w    = (const float*)d_in[7];
    const float* qkv_b    = (const float*)d_in[8];
    const float* proj_w   = (const float*)d_in[9];
    const float* proj_b   = (const float*)d_in[10];

    float* out    = (float*)d_out;
    float* outVd  = out;
    float* outEnc = out + 393216;
    float* outRm  = out + 393216 + 12544;

    float* ws = (float*)d_ws;
    // flat layout, no overlays (~57.7 MB)
    float*    cnq    = ws + 0;                          // 8,192
    float4*   cand   = (float4*)(ws + 8192);            // 1,605,632 fl
    char*     CBq    = (char*)(ws + 1613824);           // 1,572,864 fl
    char*     Aq     = (char*)(ws + 3186688);           // 2,408,448 fl
    ushort_t* attHi  = (ushort_t*)(ws + 5595136);       // 30,720 fl
    char*     exq    = (char*)(ws + 5625856);           // 3,072 fl
    ushort_t* wqkvF  = (ushort_t*)(ws + 5628928);       // 884,736 fl
    ushort_t* wprojF = (ushort_t*)(ws + 6513664);       // 294,912 fl
    int*      idx    = (int*)(ws + 6808576);            // 12,544
    float*    XW     = ws + 6821120;                    // 200,704
    float*    sm     = ws + 7021824;                    // 12,544
    ushort_t* Vhi    = (ushort_t*)(ws + 7034368);       // 4,816,896 fl
    float*    OUTC   = ws + 11851264;                   // 1,003,520
    ushort_t* seqF   = (ushort_t*)(ws + 12854784);      // 196,608 fl
    float*    qkvb   = ws + 13051392;                   // 1,179,648
    ushort_t* attnbF = (ushort_t*)(ws + 14231040);      // 196,608 fl -> 14,427,648

    hipLaunchKernelGGL(cbq_kernel, dim3(512), dim3(256), 0, stream, codebook, CBq, cnq);
    hipLaunchKernelGGL(aq_kernel, dim3(784), dim3(256), 0, stream, in_feas, Aq);
    hipLaunchKernelGGL(wsplit_kernel, dim3(33), dim3(256), 0, stream, att_w, ex_w, attHi, exq);
    hipLaunchKernelGGL(wgemm_split_kernel, dim3(1152), dim3(256), 0, stream,
                       qkv_w, proj_w, wqkvF, wprojF);
    hipLaunchKernelGGL(vq_i8_kernel, dim3(8, 196), dim3(256), 0, stream, Aq, CBq, cnq, cand);
    hipLaunchKernelGGL(convgemm_i8_kernel, dim3(98), dim3(256), 0, stream, Aq, exq, XW);
    hipLaunchKernelGGL(rescore_kernel, dim3(M_ / 4), dim3(256), 0, stream,
                       cand, in_feas, codebook, idx, outEnc);
    hipLaunchKernelGGL(mm_finish_kernel, dim3(B_), dim3(256), 0, stream, XW, ex_b, sm);
    hipLaunchKernelGGL(vqf_split_kernel, dim3(784), dim3(256), 0, stream,
                       in_feas, codebook, idx, sm, Vhi);
    hipLaunchKernelGGL((convgemm_kernel<5>), dim3(98), dim3(256), 0, stream, Vhi, attHi, OUTC);
    hipLaunchKernelGGL(rm_finish_kernel, dim3(392), dim3(256), 0, stream, OUTC, att_b, outRm);
    hipLaunchKernelGGL(regions_kernel, dim3(B_, 3), dim3(256), 0, stream, Vhi, outRm, seqF);
    hipLaunchKernelGGL((gemm_frag_kernel<8>), dim3(4, 18), dim3(256), 0, stream,
                       seqF, wqkvF, qkv_b, qkvb, 2304);
    hipLaunchKernelGGL(attn_kernel, dim3(BP_, NH_), dim3(256), 0, stream, qkvb, attnbF);
    hipLaunchKernelGGL((gemm_frag_kernel<8>), dim3(4, 6), dim3(256), 0, stream,
                       attnbF, wprojF, proj_b, outVd, 768);
}